// Round 1
// baseline (525.745 us; speedup 1.0000x reference)
//
#include <hip/hip_runtime.h>

// SBSM block: B=2, C=48, H=W=64, L=4096, DI=96, DS=16, DCONV=4, DTR=3, HF=96
#define DEV __device__ __forceinline__

DEV float siluf(float x){ return x / (1.f + __expf(-x)); }
DEV float softplusf(float x){ return fmaxf(x, 0.f) + log1pf(expf(-fabsf(x))); }
DEV float geluf(float x){ return 0.5f * x * (1.f + erff(x * 0.70710678118654752440f)); }

// ---------------- K0: LN over C at each position, write position-major (B,HW,48)
__global__ __launch_bounds__(256) void k0_ln_pos(const float* __restrict__ x,
    const float* __restrict__ w, const float* __restrict__ bia, float* __restrict__ out){
  int idx = blockIdx.x*256 + threadIdx.x;      // b*4096 + p
  if (idx >= 2*4096) return;
  int b = idx >> 12, p = idx & 4095;
  const float* xp = x + (size_t)b*48*4096 + p;
  float v[48]; float mu = 0.f;
  #pragma unroll
  for (int c = 0; c < 48; c++){ v[c] = xp[c*4096]; mu += v[c]; }
  mu *= (1.f/48.f);
  float var = 0.f;
  #pragma unroll
  for (int c = 0; c < 48; c++){ float d = v[c]-mu; var += d*d; }
  var *= (1.f/48.f);
  float rs = rsqrtf(var + 1e-5f);
  float* o = out + (size_t)idx*48;
  #pragma unroll
  for (int c = 0; c < 48; c++) o[c] = (v[c]-mu)*rs*w[c] + bia[c];
}

// ---------------- K1: snake gather + posenc + LN(mln) + inproj (48->192) -> xz (B,L,192)
__global__ __launch_bounds__(256) void k1_min(const float* __restrict__ xn_pos,
    const float* __restrict__ mw, const float* __restrict__ mb,
    const float* __restrict__ inproj, float* __restrict__ xz, int dir){
  __shared__ float Wl[192*48];
  __shared__ float Vl[48][64];
  int b = blockIdx.x >> 6, tile = blockIdx.x & 63;
  int tid = threadIdx.x;
  for (int i = tid; i < 192*48; i += 256) Wl[i] = inproj[i];
  if (tid < 64){
    int t = tile*64 + tid;
    int h, w;
    if (dir == 0){ h = t >> 6; int wp = t & 63; w = (h & 1) ? 63 - wp : wp; }
    else         { w = t >> 6; int hp = t & 63; h = (w & 1) ? 63 - hp : hp; }
    int p = h*64 + w;
    const float* row = xn_pos + ((size_t)b*4096 + p)*48;
    float v[48]; float mu = 0.f;
    #pragma unroll
    for (int c = 0; c < 48; c++){
      int k = c >> 1;
      float ang = (float)t * expf(-(float)(2*k) * (9.210340371976184f/48.f));
      float pe = (c & 1) ? cosf(ang) : sinf(ang);
      v[c] = row[c] + pe; mu += v[c];
    }
    mu *= (1.f/48.f);
    float var = 0.f;
    #pragma unroll
    for (int c = 0; c < 48; c++){ float d = v[c]-mu; var += d*d; }
    var *= (1.f/48.f);
    float rs = rsqrtf(var + 1e-5f);
    #pragma unroll
    for (int c = 0; c < 48; c++) Vl[c][tid] = (v[c]-mu)*rs*mw[c] + mb[c];
  }
  __syncthreads();
  float* xzb = xz + ((size_t)b*4096 + tile*64)*192;
  for (int i = tid; i < 48*64; i += 256){      // 48 j-groups of 4 x 64 rows
    int r = i & 63, jb = i >> 6; int j0 = jb*4;
    float a0=0,a1=0,a2=0,a3=0;
    #pragma unroll 4
    for (int c = 0; c < 48; c++){
      float vv = Vl[c][r];
      a0 += vv*Wl[(j0+0)*48+c];
      a1 += vv*Wl[(j0+1)*48+c];
      a2 += vv*Wl[(j0+2)*48+c];
      a3 += vv*Wl[(j0+3)*48+c];
    }
    float* o = xzb + (size_t)r*192 + j0;
    o[0]=a0; o[1]=a1; o[2]=a2; o[3]=a3;
  }
}

// ---------------- K2: causal dwconv4 + silu -> xc; xproj (96->35); dt=softplus; split B/C
__global__ __launch_bounds__(256) void k2_convdt(const float* __restrict__ xz,
    const float* __restrict__ convw, const float* __restrict__ convb,
    const float* __restrict__ xproj, const float* __restrict__ dtw, const float* __restrict__ dtbp,
    float* __restrict__ xc, float* __restrict__ dt, float* __restrict__ Bm, float* __restrict__ Cm){
  __shared__ float xcl[96][65];
  __shared__ union UU {
    float xm[96][67];
    struct { float xdbl[35][64]; float xw[35*96]; float dw[96*3]; float db[96]; } p;
  } u;
  __shared__ float cw[96*4], cbv[96];
  int b = blockIdx.x >> 6, tile = blockIdx.x & 63;
  int t0 = tile*64;
  int tid = threadIdx.x;
  const float* xzb = xz + (size_t)b*4096*192;
  for (int i = tid; i < 96*67; i += 256){
    int tl = i / 96, d = i % 96;
    int t = t0 + tl - 3;
    u.xm[d][tl] = (t >= 0) ? xzb[(size_t)t*192 + d] : 0.f;
  }
  for (int i = tid; i < 96*4; i += 256) cw[i] = convw[i];
  for (int i = tid; i < 96;   i += 256) cbv[i] = convb[i];
  __syncthreads();
  for (int i = tid; i < 96*64; i += 256){      // conv: lanes on t
    int d = i >> 6, t = i & 63;
    float acc = cbv[d];
    #pragma unroll
    for (int k = 0; k < 4; k++) acc += cw[d*4+k] * u.xm[d][t+k];
    xcl[d][t] = siluf(acc);
  }
  __syncthreads();
  float* xcg = xc + ((size_t)b*4096 + t0)*96;
  for (int i = tid; i < 64*96; i += 256){      // coalesced xc write (B,L,96)
    int t = i / 96, d = i % 96;
    xcg[(size_t)t*96 + d] = xcl[d][t];
  }
  for (int i = tid; i < 35*96; i += 256) u.p.xw[i] = xproj[i];
  for (int i = tid; i < 96*3;  i += 256) u.p.dw[i] = dtw[i];
  for (int i = tid; i < 96;    i += 256) u.p.db[i] = dtbp[i];
  __syncthreads();
  for (int i = tid; i < 35*64; i += 256){      // x_dbl: lanes on t
    int j = i >> 6, t = i & 63;
    float acc = 0.f;
    #pragma unroll 4
    for (int d = 0; d < 96; d++) acc += xcl[d][t] * u.p.xw[j*96+d];
    u.p.xdbl[j][t] = acc;
  }
  __syncthreads();
  float* dtg = dt + ((size_t)b*4096 + t0)*96;
  for (int i = tid; i < 64*96; i += 256){
    int t = i / 96, d = i % 96;
    float v = u.p.db[d];
    #pragma unroll
    for (int r = 0; r < 3; r++) v += u.p.xdbl[r][t] * u.p.dw[d*3+r];
    dtg[(size_t)t*96 + d] = softplusf(v);
  }
  float* Bg = Bm + ((size_t)b*4096 + t0)*16;
  float* Cg = Cm + ((size_t)b*4096 + t0)*16;
  for (int i = tid; i < 64*16; i += 256){
    int t = i / 16, s = i % 16;
    Bg[(size_t)t*16+s] = u.p.xdbl[3+s][t];
    Cg[(size_t)t*16+s] = u.p.xdbl[19+s][t];
  }
}

// ---------------- K3: chunk-local scan pass 1 -> (P, S) per chunk of 64
__global__ __launch_bounds__(256) void k3_scan1(const float* __restrict__ dt,
    const float* __restrict__ xc, const float* __restrict__ Bm,
    const float* __restrict__ Alog, float* __restrict__ P, float* __restrict__ S){
  __shared__ float dts[8][96], xcs[8][96], Bs[8][16];
  int b = blockIdx.x >> 6, ch = blockIdx.x & 63;
  int tid = threadIdx.x;
  int s = tid & 15, dg = tid >> 4;
  float A[6], h[6] = {0,0,0,0,0,0}, p[6] = {1,1,1,1,1,1};
  #pragma unroll
  for (int k = 0; k < 6; k++) A[k] = -__expf(Alog[(dg + 16*k)*16 + s]);
  size_t base = (size_t)b*4096 + ch*64;
  for (int st0 = 0; st0 < 64; st0 += 8){
    __syncthreads();
    for (int i = tid; i < 8*96; i += 256){
      int tl = i / 96, d = i % 96;
      dts[tl][d] = dt[(base + st0 + tl)*96 + d];
      xcs[tl][d] = xc[(base + st0 + tl)*96 + d];
    }
    for (int i = tid; i < 8*16; i += 256){
      int tl = i / 16, ss = i % 16;
      Bs[tl][ss] = Bm[(base + st0 + tl)*16 + ss];
    }
    __syncthreads();
    #pragma unroll
    for (int st = 0; st < 8; st++){
      float bm = Bs[st][s];
      #pragma unroll
      for (int k = 0; k < 6; k++){
        int d = dg + 16*k;
        float dtd = dts[st][d];
        float a = __expf(dtd * A[k]);
        h[k] = a*h[k] + dtd * xcs[st][d] * bm;
        p[k] *= a;
      }
    }
  }
  size_t ob = ((size_t)b*64 + ch)*1536;
  #pragma unroll
  for (int k = 0; k < 6; k++){
    P[ob + tid + 256*k] = p[k];
    S[ob + tid + 256*k] = h[k];
  }
}

// ---------------- K4: sequential chunk combine -> per-chunk initial states
__global__ __launch_bounds__(512) void k4_comb(const float* __restrict__ P,
    const float* __restrict__ S, float* __restrict__ Hin){
  int b = blockIdx.x;
  int tid = threadIdx.x;
  size_t base = (size_t)b*64*1536;
  int i0 = tid, i1 = tid+512, i2 = tid+1024;
  float h0=0.f, h1=0.f, h2=0.f;
  float p0 = P[base+i0], s0 = S[base+i0];
  float p1 = P[base+i1], s1 = S[base+i1];
  float p2 = P[base+i2], s2 = S[base+i2];
  for (int c = 0; c < 64; c++){
    float np0=0,ns0=0,np1=0,ns1=0,np2=0,ns2=0;
    if (c < 63){
      size_t nb = base + (size_t)(c+1)*1536;
      np0=P[nb+i0]; ns0=S[nb+i0]; np1=P[nb+i1]; ns1=S[nb+i1]; np2=P[nb+i2]; ns2=S[nb+i2];
    }
    size_t cb = base + (size_t)c*1536;
    Hin[cb+i0]=h0; Hin[cb+i1]=h1; Hin[cb+i2]=h2;
    h0 = p0*h0 + s0; h1 = p1*h1 + s1; h2 = p2*h2 + s2;
    p0=np0; s0=ns0; p1=np1; s1=ns1; p2=np2; s2=ns2;
  }
}

// ---------------- K5: pass 3 rescan + y = sum_s h*C, then (y + xc*D)*silu(z)
__global__ __launch_bounds__(256) void k5_scan2(const float* __restrict__ dt,
    const float* __restrict__ xc, const float* __restrict__ Bm, const float* __restrict__ Cm,
    const float* __restrict__ Alog, const float* __restrict__ Dp,
    const float* __restrict__ xz, const float* __restrict__ Hin, float* __restrict__ yout){
  __shared__ float dts[8][96], xcs[8][96], Bs[8][16], Cs[8][16], yl[8][96];
  int b = blockIdx.x >> 6, ch = blockIdx.x & 63;
  int tid = threadIdx.x;
  int s = tid & 15, dg = tid >> 4;
  float A[6], h[6];
  size_t hb = ((size_t)b*64 + ch)*1536;
  #pragma unroll
  for (int k = 0; k < 6; k++){
    A[k] = -__expf(Alog[(dg + 16*k)*16 + s]);
    h[k] = Hin[hb + tid + 256*k];
  }
  size_t base = (size_t)b*4096 + ch*64;
  for (int st0 = 0; st0 < 64; st0 += 8){
    __syncthreads();
    for (int i = tid; i < 8*96; i += 256){
      int tl = i / 96, d = i % 96;
      dts[tl][d] = dt[(base + st0 + tl)*96 + d];
      xcs[tl][d] = xc[(base + st0 + tl)*96 + d];
    }
    for (int i = tid; i < 8*16; i += 256){
      int tl = i / 16, ss = i % 16;
      Bs[tl][ss] = Bm[(base + st0 + tl)*16 + ss];
      Cs[tl][ss] = Cm[(base + st0 + tl)*16 + ss];
    }
    __syncthreads();
    #pragma unroll
    for (int st = 0; st < 8; st++){
      float bm = Bs[st][s], cm = Cs[st][s];
      #pragma unroll
      for (int k = 0; k < 6; k++){
        int d = dg + 16*k;
        float dtd = dts[st][d];
        float a = __expf(dtd * A[k]);
        h[k] = a*h[k] + dtd * xcs[st][d] * bm;
        float py = h[k]*cm;
        py += __shfl_xor(py, 1);
        py += __shfl_xor(py, 2);
        py += __shfl_xor(py, 4);
        py += __shfl_xor(py, 8);
        if (s == 0) yl[st][d] = py;
      }
    }
    __syncthreads();
    for (int i = tid; i < 8*96; i += 256){
      int tl = i / 96, d = i % 96;
      size_t t = base + st0 + tl;
      float z = xz[t*192 + 96 + d];
      yout[t*96 + d] = (yl[tl][d] + xcs[tl][d]*Dp[d]) * siluf(z);
    }
  }
}

// ---------------- K6: un-snake + outproj (96->48) both dirs + residual -> xmid
__global__ __launch_bounds__(256) void k6_outproj(const float* __restrict__ x,
    const float* __restrict__ y1, const float* __restrict__ y2,
    const float* __restrict__ op1, const float* __restrict__ op2, float* __restrict__ xmid){
  __shared__ float wl[48*96];
  __shared__ float ylds[64][97];
  int b = blockIdx.x >> 6, h = blockIdx.x & 63;
  int tid = threadIdx.x;
  float acc[3][4];
  #pragma unroll
  for (int a = 0; a < 3; a++) { acc[a][0]=0; acc[a][1]=0; acc[a][2]=0; acc[a][3]=0; }
  for (int pass = 0; pass < 2; pass++){
    __syncthreads();
    const float* op = pass ? op2 : op1;
    const float* y  = pass ? y2  : y1;
    for (int i = tid; i < 48*96; i += 256) wl[i] = op[i];
    if (pass == 0){
      for (int i = tid; i < 64*96; i += 256){
        int wp = i / 96, d = i % 96;
        int wsp = (h & 1) ? 63 - wp : wp;
        ylds[wsp][d] = y[((size_t)b*4096 + h*64 + wp)*96 + d];
      }
    } else {
      for (int i = tid; i < 64*96; i += 256){
        int w = i / 96, d = i % 96;
        int t = w*64 + ((w & 1) ? 63 - h : h);
        ylds[w][d] = y[((size_t)b*4096 + t)*96 + d];
      }
    }
    __syncthreads();
    for (int it = 0; it < 3; it++){
      int i = tid + it*256;
      int w = i & 63, cb = i >> 6;
      #pragma unroll 4
      for (int d = 0; d < 96; d++){
        float yv = ylds[w][d];
        #pragma unroll
        for (int q = 0; q < 4; q++) acc[it][q] += yv * wl[(cb*4+q)*96 + d];
      }
    }
  }
  for (int it = 0; it < 3; it++){
    int i = tid + it*256;
    int w = i & 63, cb = i >> 6;
    #pragma unroll
    for (int q = 0; q < 4; q++){
      int c = cb*4 + q;
      size_t idx = (((size_t)b*48 + c)*64 + h)*64 + w;
      xmid[idx] = x[idx] + acc[it][q];
    }
  }
}

// ---------------- K7: LN(n2) + 1x1 conv f_pin (48->192) -> xp (B,192,H,W)
__global__ __launch_bounds__(256) void k7_ln_pin(const float* __restrict__ xmid,
    const float* __restrict__ nw, const float* __restrict__ nb,
    const float* __restrict__ pin, float* __restrict__ xp){
  __shared__ float wl[192*48];
  __shared__ float xl[48][64];
  int b = blockIdx.x >> 6, h = blockIdx.x & 63;
  int tid = threadIdx.x;
  for (int i = tid; i < 192*48; i += 256) wl[i] = pin[i];
  if (tid < 64){
    int w = tid;
    float v[48]; float mu = 0.f;
    #pragma unroll
    for (int c = 0; c < 48; c++){ v[c] = xmid[(((size_t)b*48+c)*64 + h)*64 + w]; mu += v[c]; }
    mu *= (1.f/48.f);
    float var = 0.f;
    #pragma unroll
    for (int c = 0; c < 48; c++){ float d = v[c]-mu; var += d*d; }
    var *= (1.f/48.f);
    float rs = rsqrtf(var + 1e-5f);
    #pragma unroll
    for (int c = 0; c < 48; c++) xl[c][w] = (v[c]-mu)*rs*nw[c] + nb[c];
  }
  __syncthreads();
  for (int i = tid; i < 48*64; i += 256){      // 48 o-groups of 4 x 64 w
    int w = i & 63, ob = i >> 6; int o0 = ob*4;
    float a0=0,a1=0,a2=0,a3=0;
    #pragma unroll 4
    for (int c = 0; c < 48; c++){
      float xv = xl[c][w];
      a0 += xv*wl[(o0+0)*48+c];
      a1 += xv*wl[(o0+1)*48+c];
      a2 += xv*wl[(o0+2)*48+c];
      a3 += xv*wl[(o0+3)*48+c];
    }
    xp[(((size_t)b*192 + o0+0)*64 + h)*64 + w] = a0;
    xp[(((size_t)b*192 + o0+1)*64 + h)*64 + w] = a1;
    xp[(((size_t)b*192 + o0+2)*64 + h)*64 + w] = a2;
    xp[(((size_t)b*192 + o0+3)*64 + h)*64 + w] = a3;
  }
}

// ---------------- K8: 2x2 avg pool of original x -> (B,48,32,32)
__global__ __launch_bounds__(256) void k8_pool(const float* __restrict__ x, float* __restrict__ yp){
  int idx = blockIdx.x*256 + threadIdx.x;
  if (idx >= 2*48*32*32) return;
  int j = idx & 31, i = (idx >> 5) & 31, c = (idx >> 10) % 48, b = idx / (48*1024);
  const float* xb = x + (((size_t)b*48 + c)*64 + 2*i)*64 + 2*j;
  yp[idx] = 0.25f*(xb[0] + xb[1] + xb[64] + xb[65]);
}

// ---------------- K9: direct 3x3 conv 48->48 on 32x32, split out-channels in halves
__global__ __launch_bounds__(256) void k9_conv3(const float* __restrict__ in,
    const float* __restrict__ wgt, const float* __restrict__ bias, float* __restrict__ out){
  __shared__ float sin_[48][3][34];
  __shared__ float wl[24*48*9];
  int bid = blockIdx.x;
  int coh = bid & 1, i0 = (bid >> 1) & 31, b = bid >> 6;
  int tid = threadIdx.x;
  for (int i = tid; i < 24*48*9; i += 256) wl[i] = wgt[coh*24*48*9 + i];
  for (int i = tid; i < 48*3*34; i += 256){
    int jx = i % 34, ky = (i/34) % 3, ci = i/(34*3);
    int r = i0 + ky - 1, j = jx - 1;
    float v = 0.f;
    if (r >= 0 && r < 32 && j >= 0 && j < 32)
      v = in[(((size_t)b*48 + ci)*32 + r)*32 + j];
    sin_[ci][ky][jx] = v;
  }
  __syncthreads();
  for (int i = tid; i < 24*32; i += 256){
    int j = i & 31, col = i >> 5;
    float acc = bias[coh*24 + col];
    for (int ci = 0; ci < 48; ci++){
      const float* wp = wl + ((size_t)col*48 + ci)*9;
      #pragma unroll
      for (int ky = 0; ky < 3; ky++)
        #pragma unroll
        for (int kx = 0; kx < 3; kx++)
          acc += sin_[ci][ky][j+kx] * wp[ky*3+kx];
    }
    out[(((size_t)b*48 + coh*24 + col)*32 + i0)*32 + j] = acc;
  }
}

// ---------------- K10: LN over C + relu on (B,48,32,32)
__global__ __launch_bounds__(256) void k10_lnrelu(const float* __restrict__ in,
    const float* __restrict__ w, const float* __restrict__ bia, float* __restrict__ out){
  int idx = blockIdx.x*256 + threadIdx.x;
  if (idx >= 2*1024) return;
  int b = idx >> 10, p = idx & 1023;
  const float* ip = in + (size_t)b*48*1024 + p;
  float v[48]; float mu = 0.f;
  #pragma unroll
  for (int c = 0; c < 48; c++){ v[c] = ip[c*1024]; mu += v[c]; }
  mu *= (1.f/48.f);
  float var = 0.f;
  #pragma unroll
  for (int c = 0; c < 48; c++){ float d = v[c]-mu; var += d*d; }
  var *= (1.f/48.f);
  float rs = rsqrtf(var + 1e-5f);
  float* op = out + (size_t)b*48*1024 + p;
  #pragma unroll
  for (int c = 0; c < 48; c++){
    float t = (v[c]-mu)*rs*w[c] + bia[c];
    op[c*1024] = fmaxf(t, 0.f);
  }
}

// ---------------- K13: depthwise 3x3, pad 1, CH channels, 64x64
__global__ __launch_bounds__(256) void k13_dw(const float* __restrict__ in,
    const float* __restrict__ wgt, float* __restrict__ out, int CH){
  int idx = blockIdx.x*256 + threadIdx.x;
  if (idx >= 2*CH*4096) return;
  int w = idx & 63, h = (idx >> 6) & 63, c = (idx >> 12) % CH, b = idx / (CH*4096);
  const float* ip = in + ((size_t)b*CH + c)*4096;
  const float* wp = wgt + c*9;
  float acc = 0.f;
  #pragma unroll
  for (int ky = 0; ky < 3; ky++){
    int hh = h + ky - 1;
    if (hh < 0 || hh > 63) continue;
    #pragma unroll
    for (int kx = 0; kx < 3; kx++){
      int ww = w + kx - 1;
      if (ww < 0 || ww > 63) continue;
      acc += wp[ky*3+kx] * ip[hh*64 + ww];
    }
  }
  out[idx] = acc;
}

// ---------------- K14: 1x1 conv f_fus over concat(xd[:96], upsample(yb)) -> x1 (96 ch)
__global__ __launch_bounds__(256) void k14_fus(const float* __restrict__ xd,
    const float* __restrict__ yb, const float* __restrict__ fus, float* __restrict__ x1){
  __shared__ float wl[48*144];
  __shared__ float al[96][64];
  __shared__ float yl[48][32];
  int bid = blockIdx.x;
  int oh = bid & 1, h = (bid >> 1) & 63, b = bid >> 7;
  int tid = threadIdx.x;
  for (int i = tid; i < 48*144; i += 256) wl[i] = fus[(size_t)oh*48*144 + i];
  for (int i = tid; i < 96*64; i += 256){
    int ci = i >> 6, w = i & 63;
    al[ci][w] = xd[(((size_t)b*192 + ci)*64 + h)*64 + w];
  }
  for (int i = tid; i < 48*32; i += 256){
    int cj = i >> 5, j = i & 31;
    yl[cj][j] = yb[(((size_t)b*48 + cj)*32 + (h >> 1))*32 + j];
  }
  __syncthreads();
  for (int it = 0; it < 3; it++){
    int i = tid + it*256;
    int w = i & 63, ob = i >> 6; int o0 = ob*4;
    float a[4] = {0,0,0,0};
    #pragma unroll 4
    for (int ci = 0; ci < 96; ci++){
      float xv = al[ci][w];
      #pragma unroll
      for (int q = 0; q < 4; q++) a[q] += xv * wl[(o0+q)*144 + ci];
    }
    int w2 = w >> 1;
    #pragma unroll 4
    for (int cj = 0; cj < 48; cj++){
      float yv = yl[cj][w2];
      #pragma unroll
      for (int q = 0; q < 4; q++) a[q] += yv * wl[(o0+q)*144 + 96 + cj];
    }
    #pragma unroll
    for (int q = 0; q < 4; q++)
      x1[(((size_t)b*96 + oh*48 + o0 + q)*64 + h)*64 + w] = a[q];
  }
}

// ---------------- K16: gelu(x1d)*x2 -> 1x1 conv f_pout (96->48) -> + xmid -> out
__global__ __launch_bounds__(256) void k16_out(const float* __restrict__ x1d,
    const float* __restrict__ xd, const float* __restrict__ pout,
    const float* __restrict__ xmid, float* __restrict__ out){
  __shared__ float wl[48*96];
  __shared__ float gl[96][64];
  int b = blockIdx.x >> 6, h = blockIdx.x & 63;
  int tid = threadIdx.x;
  for (int i = tid; i < 48*96; i += 256) wl[i] = pout[i];
  for (int i = tid; i < 96*64; i += 256){
    int ch = i >> 6, w = i & 63;
    float a  = x1d[(((size_t)b*96 + ch)*64 + h)*64 + w];
    float x2 = xd[(((size_t)b*192 + 96 + ch)*64 + h)*64 + w];
    gl[ch][w] = geluf(a) * x2;
  }
  __syncthreads();
  for (int it = 0; it < 3; it++){
    int i = tid + it*256;
    int w = i & 63, cbk = i >> 6; int c0 = cbk*4;
    float a[4] = {0,0,0,0};
    #pragma unroll 4
    for (int ch = 0; ch < 96; ch++){
      float gv = gl[ch][w];
      #pragma unroll
      for (int q = 0; q < 4; q++) a[q] += gv * wl[(c0+q)*96 + ch];
    }
    #pragma unroll
    for (int q = 0; q < 4; q++){
      size_t idx = (((size_t)b*48 + c0 + q)*64 + h)*64 + w;
      out[idx] = xmid[idx] + a[q];
    }
  }
}

extern "C" void kernel_launch(void* const* d_in, const int* in_sizes, int n_in,
                              void* d_out, int out_size, void* d_ws, size_t ws_size,
                              hipStream_t stream){
  (void)in_sizes; (void)n_in; (void)out_size; (void)ws_size;
  const float* x    = (const float*)d_in[0];
  const float* n1w  = (const float*)d_in[1];
  const float* n1b  = (const float*)d_in[2];
  const float* n2w  = (const float*)d_in[3];
  const float* n2b  = (const float*)d_in[4];
  const float* mlnw[2] = {(const float*)d_in[5], (const float*)d_in[7]};
  const float* mlnb[2] = {(const float*)d_in[6], (const float*)d_in[8]};
  const float* fln1w = (const float*)d_in[9];
  const float* fln1b = (const float*)d_in[10];
  const float* fln2w = (const float*)d_in[11];
  const float* fln2b = (const float*)d_in[12];
  const float* inproj[2]  = {(const float*)d_in[13], (const float*)d_in[22]};
  const float* convw[2]   = {(const float*)d_in[14], (const float*)d_in[23]};
  const float* convb[2]   = {(const float*)d_in[15], (const float*)d_in[24]};
  const float* xproj[2]   = {(const float*)d_in[16], (const float*)d_in[25]};
  const float* dtw[2]     = {(const float*)d_in[17], (const float*)d_in[26]};
  const float* dtbp[2]    = {(const float*)d_in[18], (const float*)d_in[27]};
  const float* Alog[2]    = {(const float*)d_in[19], (const float*)d_in[28]};
  const float* Dp[2]      = {(const float*)d_in[20], (const float*)d_in[29]};
  const float* outproj[2] = {(const float*)d_in[21], (const float*)d_in[30]};
  const float* fpin  = (const float*)d_in[31];
  const float* fdw   = (const float*)d_in[32];
  const float* ffus  = (const float*)d_in[33];
  const float* fdwa  = (const float*)d_in[34];
  const float* fpout = (const float*)d_in[35];
  const float* fc1w  = (const float*)d_in[36];
  const float* fc1b  = (const float*)d_in[37];
  const float* fc2w  = (const float*)d_in[38];
  const float* fc2b  = (const float*)d_in[39];

  float* ws = (float*)d_ws;
  size_t off = 0;
  float* xn_pos = ws + off; off += 393216;   // (B,HW,48)
  float* xz     = ws + off; off += 1572864;  // (B,L,192)  [also reused as xp]
  float* xcb    = ws + off; off += 786432;   // (B,L,96)   [xcb+dtb reused as xd]
  float* dtb    = ws + off; off += 786432;   // (B,L,96)
  float* Bmb    = ws + off; off += 131072;   // (B,L,16)
  float* Cmb    = ws + off; off += 131072;   // (B,L,16)
  float* Pb     = ws + off; off += 196608;   // (B,64,1536)
  float* Sb     = ws + off; off += 196608;
  float* Hb     = ws + off; off += 196608;
  float* y1     = ws + off; off += 786432;   // (B,L,96)   [reused as x1]
  float* y2     = ws + off; off += 786432;   // (B,L,96)   [reused as x1d]
  float* xmid   = ws + off; off += 393216;   // (B,48,64,64)
  float* ypb    = ws + off; off += 98304;    // (B,48,32,32)
  float* ta     = ws + off; off += 98304;
  float* tbuf   = ws + off; off += 98304;
  float* ybb    = ws + off; off += 98304;
  float* xpb  = xz;     // (B,192,64,64), written after xz is dead
  float* xdb  = xcb;    // (B,192,64,64) spans xcb+dtb
  float* x1b  = y1;     // (B,96,64,64)
  float* x1db = y2;     // (B,96,64,64)

  k0_ln_pos<<<32,256,0,stream>>>(x, n1w, n1b, xn_pos);
  for (int dir = 0; dir < 2; dir++){
    k1_min   <<<128,256,0,stream>>>(xn_pos, mlnw[dir], mlnb[dir], inproj[dir], xz, dir);
    k2_convdt<<<128,256,0,stream>>>(xz, convw[dir], convb[dir], xproj[dir], dtw[dir], dtbp[dir],
                                    xcb, dtb, Bmb, Cmb);
    k3_scan1 <<<128,256,0,stream>>>(dtb, xcb, Bmb, Alog[dir], Pb, Sb);
    k4_comb  <<<2,512,0,stream>>>(Pb, Sb, Hb);
    k5_scan2 <<<128,256,0,stream>>>(dtb, xcb, Bmb, Cmb, Alog[dir], Dp[dir], xz, Hb,
                                    dir ? y2 : y1);
  }
  k6_outproj<<<128,256,0,stream>>>(x, y1, y2, outproj[0], outproj[1], xmid);
  k7_ln_pin <<<128,256,0,stream>>>(xmid, n2w, n2b, fpin, xpb);
  k8_pool   <<<384,256,0,stream>>>(x, ypb);
  k9_conv3  <<<128,256,0,stream>>>(ypb, fc1w, fc1b, ta);
  k10_lnrelu<<<8,256,0,stream>>>(ta, fln1w, fln1b, tbuf);
  k9_conv3  <<<128,256,0,stream>>>(tbuf, fc2w, fc2b, ta);
  k10_lnrelu<<<8,256,0,stream>>>(ta, fln2w, fln2b, ybb);
  k13_dw    <<<6144,256,0,stream>>>(xpb, fdw, xdb, 192);
  k14_fus   <<<256,256,0,stream>>>(xdb, ybb, ffus, x1b);
  k13_dw    <<<3072,256,0,stream>>>(x1b, fdwa, x1db, 96);
  k16_out   <<<128,256,0,stream>>>(x1db, xdb, fpout, xmid, (float*)d_out);
}

// Round 2
// 525.113 us; speedup vs baseline: 1.0012x; 1.0012x over previous
//
#include <hip/hip_runtime.h>

// SBSM block: B=2, C=48, H=W=64, L=4096, DI=96, DS=16, DCONV=4, DTR=3, HF=96
#define DEV __device__ __forceinline__

DEV float siluf(float x){ return x / (1.f + __expf(-x)); }
DEV float softplusf(float x){ return fmaxf(x, 0.f) + log1pf(expf(-fabsf(x))); }
DEV float geluf(float x){ return 0.5f * x * (1.f + erff(x * 0.70710678118654752440f)); }

// ---------------- K0: LN over C at each position, write position-major (B,HW,48)
__global__ __launch_bounds__(256) void k0_ln_pos(const float* __restrict__ x,
    const float* __restrict__ w, const float* __restrict__ bia, float* __restrict__ out){
  int idx = blockIdx.x*256 + threadIdx.x;      // b*4096 + p
  if (idx >= 2*4096) return;
  int b = idx >> 12, p = idx & 4095;
  const float* xp = x + (size_t)b*48*4096 + p;
  float v[48]; float mu = 0.f;
  #pragma unroll
  for (int c = 0; c < 48; c++){ v[c] = xp[c*4096]; mu += v[c]; }
  mu *= (1.f/48.f);
  float var = 0.f;
  #pragma unroll
  for (int c = 0; c < 48; c++){ float d = v[c]-mu; var += d*d; }
  var *= (1.f/48.f);
  float rs = rsqrtf(var + 1e-5f);
  float* o = out + (size_t)idx*48;
  #pragma unroll
  for (int c = 0; c < 48; c++) o[c] = (v[c]-mu)*rs*w[c] + bia[c];
}

// ---------------- K1: snake gather + posenc + LN(mln) + inproj (48->192) -> xz (B,L,192)
__global__ __launch_bounds__(256) void k1_min(const float* __restrict__ xn_pos,
    const float* __restrict__ mw, const float* __restrict__ mb,
    const float* __restrict__ inproj, float* __restrict__ xz, int dir){
  __shared__ float Wl[192*48];
  __shared__ float Vl[48][64];
  int b = blockIdx.x >> 6, tile = blockIdx.x & 63;
  int tid = threadIdx.x;
  for (int i = tid; i < 192*48; i += 256) Wl[i] = inproj[i];
  if (tid < 64){
    int t = tile*64 + tid;
    int h, w;
    if (dir == 0){ h = t >> 6; int wp = t & 63; w = (h & 1) ? 63 - wp : wp; }
    else         { w = t >> 6; int hp = t & 63; h = (w & 1) ? 63 - hp : hp; }
    int p = h*64 + w;
    const float* row = xn_pos + ((size_t)b*4096 + p)*48;
    float v[48]; float mu = 0.f;
    #pragma unroll
    for (int c = 0; c < 48; c++){
      int k = c >> 1;
      float ang = (float)t * expf(-(float)(2*k) * (9.210340371976184f/48.f));
      float pe = (c & 1) ? cosf(ang) : sinf(ang);
      v[c] = row[c] + pe; mu += v[c];
    }
    mu *= (1.f/48.f);
    float var = 0.f;
    #pragma unroll
    for (int c = 0; c < 48; c++){ float d = v[c]-mu; var += d*d; }
    var *= (1.f/48.f);
    float rs = rsqrtf(var + 1e-5f);
    #pragma unroll
    for (int c = 0; c < 48; c++) Vl[c][tid] = (v[c]-mu)*rs*mw[c] + mb[c];
  }
  __syncthreads();
  float* xzb = xz + ((size_t)b*4096 + tile*64)*192;
  for (int i = tid; i < 48*64; i += 256){      // 48 j-groups of 4 x 64 rows
    int r = i & 63, jb = i >> 6; int j0 = jb*4;
    float a0=0,a1=0,a2=0,a3=0;
    #pragma unroll 4
    for (int c = 0; c < 48; c++){
      float vv = Vl[c][r];
      a0 += vv*Wl[(j0+0)*48+c];
      a1 += vv*Wl[(j0+1)*48+c];
      a2 += vv*Wl[(j0+2)*48+c];
      a3 += vv*Wl[(j0+3)*48+c];
    }
    float* o = xzb + (size_t)r*192 + j0;
    o[0]=a0; o[1]=a1; o[2]=a2; o[3]=a3;
  }
}

// ---------------- K2: causal dwconv4 + silu -> xc; xproj (96->35); dt=softplus; split B/C
__global__ __launch_bounds__(256) void k2_convdt(const float* __restrict__ xz,
    const float* __restrict__ convw, const float* __restrict__ convb,
    const float* __restrict__ xproj, const float* __restrict__ dtw, const float* __restrict__ dtbp,
    float* __restrict__ xc, float* __restrict__ dt, float* __restrict__ Bm, float* __restrict__ Cm){
  __shared__ float xcl[96][65];
  __shared__ union UU {
    float xm[96][67];
    struct { float xdbl[35][64]; float xw[35*96]; float dw[96*3]; float db[96]; } p;
  } u;
  __shared__ float cw[96*4], cbv[96];
  int b = blockIdx.x >> 6, tile = blockIdx.x & 63;
  int t0 = tile*64;
  int tid = threadIdx.x;
  const float* xzb = xz + (size_t)b*4096*192;
  for (int i = tid; i < 96*67; i += 256){
    int tl = i / 96, d = i % 96;
    int t = t0 + tl - 3;
    u.xm[d][tl] = (t >= 0) ? xzb[(size_t)t*192 + d] : 0.f;
  }
  for (int i = tid; i < 96*4; i += 256) cw[i] = convw[i];
  for (int i = tid; i < 96;   i += 256) cbv[i] = convb[i];
  __syncthreads();
  for (int i = tid; i < 96*64; i += 256){      // conv: lanes on t
    int d = i >> 6, t = i & 63;
    float acc = cbv[d];
    #pragma unroll
    for (int k = 0; k < 4; k++) acc += cw[d*4+k] * u.xm[d][t+k];
    xcl[d][t] = siluf(acc);
  }
  __syncthreads();
  float* xcg = xc + ((size_t)b*4096 + t0)*96;
  for (int i = tid; i < 64*96; i += 256){      // coalesced xc write (B,L,96)
    int t = i / 96, d = i % 96;
    xcg[(size_t)t*96 + d] = xcl[d][t];
  }
  for (int i = tid; i < 35*96; i += 256) u.p.xw[i] = xproj[i];
  for (int i = tid; i < 96*3;  i += 256) u.p.dw[i] = dtw[i];
  for (int i = tid; i < 96;    i += 256) u.p.db[i] = dtbp[i];
  __syncthreads();
  for (int i = tid; i < 35*64; i += 256){      // x_dbl: lanes on t
    int j = i >> 6, t = i & 63;
    float acc = 0.f;
    #pragma unroll 4
    for (int d = 0; d < 96; d++) acc += xcl[d][t] * u.p.xw[j*96+d];
    u.p.xdbl[j][t] = acc;
  }
  __syncthreads();
  float* dtg = dt + ((size_t)b*4096 + t0)*96;
  for (int i = tid; i < 64*96; i += 256){
    int t = i / 96, d = i % 96;
    float v = u.p.db[d];
    #pragma unroll
    for (int r = 0; r < 3; r++) v += u.p.xdbl[r][t] * u.p.dw[d*3+r];
    dtg[(size_t)t*96 + d] = softplusf(v);
  }
  float* Bg = Bm + ((size_t)b*4096 + t0)*16;
  float* Cg = Cm + ((size_t)b*4096 + t0)*16;
  for (int i = tid; i < 64*16; i += 256){
    int t = i / 16, s = i % 16;
    Bg[(size_t)t*16+s] = u.p.xdbl[3+s][t];
    Cg[(size_t)t*16+s] = u.p.xdbl[19+s][t];
  }
}

// ---------------- K3: chunk-local scan pass 1 -> (P, S) per chunk of 64
__global__ __launch_bounds__(256) void k3_scan1(const float* __restrict__ dt,
    const float* __restrict__ xc, const float* __restrict__ Bm,
    const float* __restrict__ Alog, float* __restrict__ P, float* __restrict__ S){
  __shared__ float dts[8][96], xcs[8][96], Bs[8][16];
  int b = blockIdx.x >> 6, ch = blockIdx.x & 63;
  int tid = threadIdx.x;
  int s = tid & 15, dg = tid >> 4;
  float A[6], h[6] = {0,0,0,0,0,0}, p[6] = {1,1,1,1,1,1};
  #pragma unroll
  for (int k = 0; k < 6; k++) A[k] = -__expf(Alog[(dg + 16*k)*16 + s]);
  size_t base = (size_t)b*4096 + ch*64;
  for (int st0 = 0; st0 < 64; st0 += 8){
    __syncthreads();
    for (int i = tid; i < 8*96; i += 256){
      int tl = i / 96, d = i % 96;
      dts[tl][d] = dt[(base + st0 + tl)*96 + d];
      xcs[tl][d] = xc[(base + st0 + tl)*96 + d];
    }
    for (int i = tid; i < 8*16; i += 256){
      int tl = i / 16, ss = i % 16;
      Bs[tl][ss] = Bm[(base + st0 + tl)*16 + ss];
    }
    __syncthreads();
    #pragma unroll
    for (int st = 0; st < 8; st++){
      float bm = Bs[st][s];
      #pragma unroll
      for (int k = 0; k < 6; k++){
        int d = dg + 16*k;
        float dtd = dts[st][d];
        float a = __expf(dtd * A[k]);
        h[k] = a*h[k] + dtd * xcs[st][d] * bm;
        p[k] *= a;
      }
    }
  }
  size_t ob = ((size_t)b*64 + ch)*1536;
  #pragma unroll
  for (int k = 0; k < 6; k++){
    P[ob + tid + 256*k] = p[k];
    S[ob + tid + 256*k] = h[k];
  }
}

// ---------------- K4: sequential chunk combine -> per-chunk initial states
__global__ __launch_bounds__(512) void k4_comb(const float* __restrict__ P,
    const float* __restrict__ S, float* __restrict__ Hin){
  int b = blockIdx.x;
  int tid = threadIdx.x;
  size_t base = (size_t)b*64*1536;
  int i0 = tid, i1 = tid+512, i2 = tid+1024;
  float h0=0.f, h1=0.f, h2=0.f;
  float p0 = P[base+i0], s0 = S[base+i0];
  float p1 = P[base+i1], s1 = S[base+i1];
  float p2 = P[base+i2], s2 = S[base+i2];
  for (int c = 0; c < 64; c++){
    float np0=0,ns0=0,np1=0,ns1=0,np2=0,ns2=0;
    if (c < 63){
      size_t nb = base + (size_t)(c+1)*1536;
      np0=P[nb+i0]; ns0=S[nb+i0]; np1=P[nb+i1]; ns1=S[nb+i1]; np2=P[nb+i2]; ns2=S[nb+i2];
    }
    size_t cb = base + (size_t)c*1536;
    Hin[cb+i0]=h0; Hin[cb+i1]=h1; Hin[cb+i2]=h2;
    h0 = p0*h0 + s0; h1 = p1*h1 + s1; h2 = p2*h2 + s2;
    p0=np0; s0=ns0; p1=np1; s1=ns1; p2=np2; s2=ns2;
  }
}

// ---------------- K5: pass 3 rescan + y = sum_s h*C, then (y + xc*D)*silu(z)
__global__ __launch_bounds__(256) void k5_scan2(const float* __restrict__ dt,
    const float* __restrict__ xc, const float* __restrict__ Bm, const float* __restrict__ Cm,
    const float* __restrict__ Alog, const float* __restrict__ Dp,
    const float* __restrict__ xz, const float* __restrict__ Hin, float* __restrict__ yout){
  __shared__ float dts[8][96], xcs[8][96], Bs[8][16], Cs[8][16], yl[8][96];
  int b = blockIdx.x >> 6, ch = blockIdx.x & 63;
  int tid = threadIdx.x;
  int s = tid & 15, dg = tid >> 4;
  float A[6], h[6];
  size_t hb = ((size_t)b*64 + ch)*1536;
  #pragma unroll
  for (int k = 0; k < 6; k++){
    A[k] = -__expf(Alog[(dg + 16*k)*16 + s]);
    h[k] = Hin[hb + tid + 256*k];
  }
  size_t base = (size_t)b*4096 + ch*64;
  for (int st0 = 0; st0 < 64; st0 += 8){
    __syncthreads();
    for (int i = tid; i < 8*96; i += 256){
      int tl = i / 96, d = i % 96;
      dts[tl][d] = dt[(base + st0 + tl)*96 + d];
      xcs[tl][d] = xc[(base + st0 + tl)*96 + d];
    }
    for (int i = tid; i < 8*16; i += 256){
      int tl = i / 16, ss = i % 16;
      Bs[tl][ss] = Bm[(base + st0 + tl)*16 + ss];
      Cs[tl][ss] = Cm[(base + st0 + tl)*16 + ss];
    }
    __syncthreads();
    #pragma unroll
    for (int st = 0; st < 8; st++){
      float bm = Bs[st][s], cm = Cs[st][s];
      #pragma unroll
      for (int k = 0; k < 6; k++){
        int d = dg + 16*k;
        float dtd = dts[st][d];
        float a = __expf(dtd * A[k]);
        h[k] = a*h[k] + dtd * xcs[st][d] * bm;
        float py = h[k]*cm;
        py += __shfl_xor(py, 1);
        py += __shfl_xor(py, 2);
        py += __shfl_xor(py, 4);
        py += __shfl_xor(py, 8);
        if (s == 0) yl[st][d] = py;
      }
    }
    __syncthreads();
    for (int i = tid; i < 8*96; i += 256){
      int tl = i / 96, d = i % 96;
      size_t t = base + st0 + tl;
      float z = xz[t*192 + 96 + d];
      yout[t*96 + d] = (yl[tl][d] + xcs[tl][d]*Dp[d]) * siluf(z);
    }
  }
}

// ---------------- K6: un-snake + outproj (96->48) both dirs + residual -> xmid
__global__ __launch_bounds__(256) void k6_outproj(const float* __restrict__ x,
    const float* __restrict__ y1, const float* __restrict__ y2,
    const float* __restrict__ op1, const float* __restrict__ op2, float* __restrict__ xmid){
  __shared__ float wl[48*96];
  __shared__ float ylds[64][97];
  int b = blockIdx.x >> 6, h = blockIdx.x & 63;
  int tid = threadIdx.x;
  float acc[3][4];
  #pragma unroll
  for (int a = 0; a < 3; a++) { acc[a][0]=0; acc[a][1]=0; acc[a][2]=0; acc[a][3]=0; }
  for (int pass = 0; pass < 2; pass++){
    __syncthreads();
    const float* op = pass ? op2 : op1;
    const float* y  = pass ? y2  : y1;
    for (int i = tid; i < 48*96; i += 256) wl[i] = op[i];
    if (pass == 0){
      for (int i = tid; i < 64*96; i += 256){
        int wp = i / 96, d = i % 96;
        int wsp = (h & 1) ? 63 - wp : wp;
        ylds[wsp][d] = y[((size_t)b*4096 + h*64 + wp)*96 + d];
      }
    } else {
      for (int i = tid; i < 64*96; i += 256){
        int w = i / 96, d = i % 96;
        int t = w*64 + ((w & 1) ? 63 - h : h);
        ylds[w][d] = y[((size_t)b*4096 + t)*96 + d];
      }
    }
    __syncthreads();
    for (int it = 0; it < 3; it++){
      int i = tid + it*256;
      int w = i & 63, cb = i >> 6;
      #pragma unroll 4
      for (int d = 0; d < 96; d++){
        float yv = ylds[w][d];
        #pragma unroll
        for (int q = 0; q < 4; q++) acc[it][q] += yv * wl[(cb*4+q)*96 + d];
      }
    }
  }
  for (int it = 0; it < 3; it++){
    int i = tid + it*256;
    int w = i & 63, cb = i >> 6;
    #pragma unroll
    for (int q = 0; q < 4; q++){
      int c = cb*4 + q;
      size_t idx = (((size_t)b*48 + c)*64 + h)*64 + w;
      xmid[idx] = x[idx] + acc[it][q];
    }
  }
}

// ---------------- K7: LN(n2) + 1x1 conv f_pin (48->192) -> xp (B,192,H,W)
__global__ __launch_bounds__(256) void k7_ln_pin(const float* __restrict__ xmid,
    const float* __restrict__ nw, const float* __restrict__ nb,
    const float* __restrict__ pin, float* __restrict__ xp){
  __shared__ float wl[192*48];
  __shared__ float xl[48][64];
  int b = blockIdx.x >> 6, h = blockIdx.x & 63;
  int tid = threadIdx.x;
  for (int i = tid; i < 192*48; i += 256) wl[i] = pin[i];
  if (tid < 64){
    int w = tid;
    float v[48]; float mu = 0.f;
    #pragma unroll
    for (int c = 0; c < 48; c++){ v[c] = xmid[(((size_t)b*48+c)*64 + h)*64 + w]; mu += v[c]; }
    mu *= (1.f/48.f);
    float var = 0.f;
    #pragma unroll
    for (int c = 0; c < 48; c++){ float d = v[c]-mu; var += d*d; }
    var *= (1.f/48.f);
    float rs = rsqrtf(var + 1e-5f);
    #pragma unroll
    for (int c = 0; c < 48; c++) xl[c][w] = (v[c]-mu)*rs*nw[c] + nb[c];
  }
  __syncthreads();
  for (int i = tid; i < 48*64; i += 256){      // 48 o-groups of 4 x 64 w
    int w = i & 63, ob = i >> 6; int o0 = ob*4;
    float a0=0,a1=0,a2=0,a3=0;
    #pragma unroll 4
    for (int c = 0; c < 48; c++){
      float xv = xl[c][w];
      a0 += xv*wl[(o0+0)*48+c];
      a1 += xv*wl[(o0+1)*48+c];
      a2 += xv*wl[(o0+2)*48+c];
      a3 += xv*wl[(o0+3)*48+c];
    }
    xp[(((size_t)b*192 + o0+0)*64 + h)*64 + w] = a0;
    xp[(((size_t)b*192 + o0+1)*64 + h)*64 + w] = a1;
    xp[(((size_t)b*192 + o0+2)*64 + h)*64 + w] = a2;
    xp[(((size_t)b*192 + o0+3)*64 + h)*64 + w] = a3;
  }
}

// ---------------- K8: 2x2 avg pool of original x -> (B,48,32,32)
__global__ __launch_bounds__(256) void k8_pool(const float* __restrict__ x, float* __restrict__ yp){
  int idx = blockIdx.x*256 + threadIdx.x;
  if (idx >= 2*48*32*32) return;
  int j = idx & 31, i = (idx >> 5) & 31, c = (idx >> 10) % 48, b = idx / (48*1024);
  const float* xb = x + (((size_t)b*48 + c)*64 + 2*i)*64 + 2*j;
  yp[idx] = 0.25f*(xb[0] + xb[1] + xb[64] + xb[65]);
}

// ---------------- K9: direct 3x3 conv 48->48 on 32x32, split out-channels in halves
__global__ __launch_bounds__(256) void k9_conv3(const float* __restrict__ in,
    const float* __restrict__ wgt, const float* __restrict__ bias, float* __restrict__ out){
  __shared__ float sin_[48][3][34];
  __shared__ float wl[24*48*9];
  int bid = blockIdx.x;
  int coh = bid & 1, i0 = (bid >> 1) & 31, b = bid >> 6;
  int tid = threadIdx.x;
  for (int i = tid; i < 24*48*9; i += 256) wl[i] = wgt[coh*24*48*9 + i];
  for (int i = tid; i < 48*3*34; i += 256){
    int jx = i % 34, ky = (i/34) % 3, ci = i/(34*3);
    int r = i0 + ky - 1, j = jx - 1;
    float v = 0.f;
    if (r >= 0 && r < 32 && j >= 0 && j < 32)
      v = in[(((size_t)b*48 + ci)*32 + r)*32 + j];
    sin_[ci][ky][jx] = v;
  }
  __syncthreads();
  for (int i = tid; i < 24*32; i += 256){
    int j = i & 31, col = i >> 5;
    float acc = bias[coh*24 + col];
    for (int ci = 0; ci < 48; ci++){
      const float* wp = wl + ((size_t)col*48 + ci)*9;
      #pragma unroll
      for (int ky = 0; ky < 3; ky++)
        #pragma unroll
        for (int kx = 0; kx < 3; kx++)
          acc += sin_[ci][ky][j+kx] * wp[ky*3+kx];
    }
    out[(((size_t)b*48 + coh*24 + col)*32 + i0)*32 + j] = acc;
  }
}

// ---------------- K10: LN over C + relu on (B,48,32,32)
__global__ __launch_bounds__(256) void k10_lnrelu(const float* __restrict__ in,
    const float* __restrict__ w, const float* __restrict__ bia, float* __restrict__ out){
  int idx = blockIdx.x*256 + threadIdx.x;
  if (idx >= 2*1024) return;
  int b = idx >> 10, p = idx & 1023;
  const float* ip = in + (size_t)b*48*1024 + p;
  float v[48]; float mu = 0.f;
  #pragma unroll
  for (int c = 0; c < 48; c++){ v[c] = ip[c*1024]; mu += v[c]; }
  mu *= (1.f/48.f);
  float var = 0.f;
  #pragma unroll
  for (int c = 0; c < 48; c++){ float d = v[c]-mu; var += d*d; }
  var *= (1.f/48.f);
  float rs = rsqrtf(var + 1e-5f);
  float* op = out + (size_t)b*48*1024 + p;
  #pragma unroll
  for (int c = 0; c < 48; c++){
    float t = (v[c]-mu)*rs*w[c] + bia[c];
    op[c*1024] = fmaxf(t, 0.f);
  }
}

// ---------------- K13: depthwise 3x3, pad 1, CH channels, 64x64
__global__ __launch_bounds__(256) void k13_dw(const float* __restrict__ in,
    const float* __restrict__ wgt, float* __restrict__ out, int CH){
  int idx = blockIdx.x*256 + threadIdx.x;
  if (idx >= 2*CH*4096) return;
  int w = idx & 63, h = (idx >> 6) & 63, c = (idx >> 12) % CH, b = idx / (CH*4096);
  const float* ip = in + ((size_t)b*CH + c)*4096;
  const float* wp = wgt + c*9;
  float acc = 0.f;
  #pragma unroll
  for (int ky = 0; ky < 3; ky++){
    int hh = h + ky - 1;
    if (hh < 0 || hh > 63) continue;
    #pragma unroll
    for (int kx = 0; kx < 3; kx++){
      int ww = w + kx - 1;
      if (ww < 0 || ww > 63) continue;
      acc += wp[ky*3+kx] * ip[hh*64 + ww];
    }
  }
  out[idx] = acc;
}

// ---------------- K14: 1x1 conv f_fus over concat(xd[:96], upsample(yb)) -> x1 (96 ch)
__global__ __launch_bounds__(256) void k14_fus(const float* __restrict__ xd,
    const float* __restrict__ yb, const float* __restrict__ fus, float* __restrict__ x1){
  __shared__ float wl[48*144];
  __shared__ float al[96][64];
  __shared__ float yl[48][32];
  int bid = blockIdx.x;
  int oh = bid & 1, h = (bid >> 1) & 63, b = bid >> 7;
  int tid = threadIdx.x;
  for (int i = tid; i < 48*144; i += 256) wl[i] = fus[(size_t)oh*48*144 + i];
  for (int i = tid; i < 96*64; i += 256){
    int ci = i >> 6, w = i & 63;
    al[ci][w] = xd[(((size_t)b*192 + ci)*64 + h)*64 + w];
  }
  for (int i = tid; i < 48*32; i += 256){
    int cj = i >> 5, j = i & 31;
    yl[cj][j] = yb[(((size_t)b*48 + cj)*32 + (h >> 1))*32 + j];
  }
  __syncthreads();
  for (int it = 0; it < 3; it++){
    int i = tid + it*256;
    int w = i & 63, ob = i >> 6; int o0 = ob*4;
    float a[4] = {0,0,0,0};
    #pragma unroll 4
    for (int ci = 0; ci < 96; ci++){
      float xv = al[ci][w];
      #pragma unroll
      for (int q = 0; q < 4; q++) a[q] += xv * wl[(o0+q)*144 + ci];
    }
    int w2 = w >> 1;
    #pragma unroll 4
    for (int cj = 0; cj < 48; cj++){
      float yv = yl[cj][w2];
      #pragma unroll
      for (int q = 0; q < 4; q++) a[q] += yv * wl[(o0+q)*144 + 96 + cj];
    }
    #pragma unroll
    for (int q = 0; q < 4; q++)
      x1[(((size_t)b*96 + oh*48 + o0 + q)*64 + h)*64 + w] = a[q];
  }
}

// ---------------- K16: gelu(x1d)*x2 -> 1x1 conv f_pout (96->48) -> + xmid -> out
__global__ __launch_bounds__(256) void k16_out(const float* __restrict__ x1d,
    const float* __restrict__ xd, const float* __restrict__ pout,
    const float* __restrict__ xmid, float* __restrict__ out){
  __shared__ float wl[48*96];
  __shared__ float gl[96][64];
  int b = blockIdx.x >> 6, h = blockIdx.x & 63;
  int tid = threadIdx.x;
  for (int i = tid; i < 48*96; i += 256) wl[i] = pout[i];
  for (int i = tid; i < 96*64; i += 256){
    int ch = i >> 6, w = i & 63;
    float a  = x1d[(((size_t)b*96 + ch)*64 + h)*64 + w];
    float x2 = xd[(((size_t)b*192 + 96 + ch)*64 + h)*64 + w];
    gl[ch][w] = geluf(a) * x2;
  }
  __syncthreads();
  for (int it = 0; it < 3; it++){
    int i = tid + it*256;
    int w = i & 63, cbk = i >> 6; int c0 = cbk*4;
    float a[4] = {0,0,0,0};
    #pragma unroll 4
    for (int ch = 0; ch < 96; ch++){
      float gv = gl[ch][w];
      #pragma unroll
      for (int q = 0; q < 4; q++) a[q] += gv * wl[(c0+q)*96 + ch];
    }
    #pragma unroll
    for (int q = 0; q < 4; q++){
      size_t idx = (((size_t)b*48 + c0 + q)*64 + h)*64 + w;
      out[idx] = xmid[idx] + a[q];
    }
  }
}

extern "C" void kernel_launch(void* const* d_in, const int* in_sizes, int n_in,
                              void* d_out, int out_size, void* d_ws, size_t ws_size,
                              hipStream_t stream){
  (void)in_sizes; (void)n_in; (void)out_size; (void)ws_size;
  const float* x    = (const float*)d_in[0];
  const float* n1w  = (const float*)d_in[1];
  const float* n1b  = (const float*)d_in[2];
  const float* n2w  = (const float*)d_in[3];
  const float* n2b  = (const float*)d_in[4];
  const float* mlnw[2] = {(const float*)d_in[5], (const float*)d_in[7]};
  const float* mlnb[2] = {(const float*)d_in[6], (const float*)d_in[8]};
  const float* fln1w = (const float*)d_in[9];
  const float* fln1b = (const float*)d_in[10];
  const float* fln2w = (const float*)d_in[11];
  const float* fln2b = (const float*)d_in[12];
  const float* inproj[2]  = {(const float*)d_in[13], (const float*)d_in[22]};
  const float* convw[2]   = {(const float*)d_in[14], (const float*)d_in[23]};
  const float* convb[2]   = {(const float*)d_in[15], (const float*)d_in[24]};
  const float* xproj[2]   = {(const float*)d_in[16], (const float*)d_in[25]};
  const float* dtw[2]     = {(const float*)d_in[17], (const float*)d_in[26]};
  const float* dtbp[2]    = {(const float*)d_in[18], (const float*)d_in[27]};
  const float* Alog[2]    = {(const float*)d_in[19], (const float*)d_in[28]};
  const float* Dp[2]      = {(const float*)d_in[20], (const float*)d_in[29]};
  const float* outproj[2] = {(const float*)d_in[21], (const float*)d_in[30]};
  const float* fpin  = (const float*)d_in[31];
  const float* fdw   = (const float*)d_in[32];
  const float* ffus  = (const float*)d_in[33];
  const float* fdwa  = (const float*)d_in[34];
  const float* fpout = (const float*)d_in[35];
  const float* fc1w  = (const float*)d_in[36];
  const float* fc1b  = (const float*)d_in[37];
  const float* fc2w  = (const float*)d_in[38];
  const float* fc2b  = (const float*)d_in[39];

  float* ws = (float*)d_ws;
  size_t off = 0;
  float* xn_pos = ws + off; off += 393216;   // (B,HW,48)
  float* xz     = ws + off; off += 1572864;  // (B,L,192)  [also reused as xp]
  float* xcb    = ws + off; off += 786432;   // (B,L,96)   [xcb+dtb reused as xd]
  float* dtb    = ws + off; off += 786432;   // (B,L,96)
  float* Bmb    = ws + off; off += 131072;   // (B,L,16)
  float* Cmb    = ws + off; off += 131072;   // (B,L,16)
  float* Pb     = ws + off; off += 196608;   // (B,64,1536)
  float* Sb     = ws + off; off += 196608;
  float* Hb     = ws + off; off += 196608;
  float* y1     = ws + off; off += 786432;   // (B,L,96)   [reused as x1]
  float* y2     = ws + off; off += 786432;   // (B,L,96)   [reused as x1d]
  float* xmid   = ws + off; off += 393216;   // (B,48,64,64)
  float* ypb    = ws + off; off += 98304;    // (B,48,32,32)
  float* ta     = ws + off; off += 98304;
  float* tbuf   = ws + off; off += 98304;
  float* ybb    = ws + off; off += 98304;
  float* xpb  = xz;     // (B,192,64,64), written after xz is dead
  float* xdb  = xcb;    // (B,192,64,64) spans xcb+dtb
  float* x1b  = y1;     // (B,96,64,64)
  float* x1db = y2;     // (B,96,64,64)

  k0_ln_pos<<<32,256,0,stream>>>(x, n1w, n1b, xn_pos);
  for (int dir = 0; dir < 2; dir++){
    k1_min   <<<128,256,0,stream>>>(xn_pos, mlnw[dir], mlnb[dir], inproj[dir], xz, dir);
    k2_convdt<<<128,256,0,stream>>>(xz, convw[dir], convb[dir], xproj[dir], dtw[dir], dtbp[dir],
                                    xcb, dtb, Bmb, Cmb);
    k3_scan1 <<<128,256,0,stream>>>(dtb, xcb, Bmb, Alog[dir], Pb, Sb);
    k4_comb  <<<2,512,0,stream>>>(Pb, Sb, Hb);
    k5_scan2 <<<128,256,0,stream>>>(dtb, xcb, Bmb, Cmb, Alog[dir], Dp[dir], xz, Hb,
                                    dir ? y2 : y1);
  }
  k6_outproj<<<128,256,0,stream>>>(x, y1, y2, outproj[0], outproj[1], xmid);
  k7_ln_pin <<<128,256,0,stream>>>(xmid, n2w, n2b, fpin, xpb);
  k8_pool   <<<384,256,0,stream>>>(x, ypb);
  k9_conv3  <<<128,256,0,stream>>>(ypb, fc1w, fc1b, ta);
  k10_lnrelu<<<8,256,0,stream>>>(ta, fln1w, fln1b, tbuf);
  k9_conv3  <<<128,256,0,stream>>>(tbuf, fc2w, fc2b, ta);
  k10_lnrelu<<<8,256,0,stream>>>(ta, fln2w, fln2b, ybb);
  k13_dw    <<<6144,256,0,stream>>>(xpb, fdw, xdb, 192);
  k14_fus   <<<256,256,0,stream>>>(xdb, ybb, ffus, x1b);
  k13_dw    <<<3072,256,0,stream>>>(x1b, fdwa, x1db, 96);
  k16_out   <<<128,256,0,stream>>>(x1db, xdb, fpout, xmid, (float*)d_out);
}

// Round 3
// 274.075 us; speedup vs baseline: 1.9183x; 1.9159x over previous
//
#include <hip/hip_runtime.h>

// SBSM block: B=2, C=48, H=W=64, L=4096, DI=96, DS=16, DCONV=4, DTR=3, HF=96
#define DEV __device__ __forceinline__

DEV float siluf(float x){ return x / (1.f + __expf(-x)); }
DEV float softplusf(float x){ return fmaxf(x, 0.f) + log1pf(expf(-fabsf(x))); }
DEV float geluf(float x){ return 0.5f * x * (1.f + erff(x * 0.70710678118654752440f)); }

// ---------------- K12: fused snake-gather + LN(n1) + posenc + LN(mln) + inproj
//                  + causal dwconv4 + silu + xproj + dt/B/C split.  One block per
//                  (bd = dir*2+b, tile of 64 t).  Boundary rows (t0-3..t0-1) recomputed.
__global__ __launch_bounds__(256) void k12_fused(const float* __restrict__ x,
    const float* __restrict__ n1w, const float* __restrict__ n1b,
    const float* __restrict__ mw0, const float* __restrict__ mb0,
    const float* __restrict__ mw1, const float* __restrict__ mb1,
    const float* __restrict__ ip0, const float* __restrict__ ip1,
    const float* __restrict__ cwp0, const float* __restrict__ cwp1,
    const float* __restrict__ cbp0, const float* __restrict__ cbp1,
    const float* __restrict__ xpp0, const float* __restrict__ xpp1,
    const float* __restrict__ dwp0, const float* __restrict__ dwp1,
    const float* __restrict__ dbp0, const float* __restrict__ dbp1,
    float* __restrict__ xc, float* __restrict__ dt,
    float* __restrict__ Bm, float* __restrict__ Cm, float* __restrict__ z){
  __shared__ float Wl[192*48];      // inproj (xm rows 0..95, z rows 96..191)
  __shared__ float Vl[48][68];      // LN'd inputs, col = local row (0..63 main, 64..66 boundary)
  __shared__ float xml[96][69];     // xm in time-local layout tl=0..66; later reused for z
  __shared__ float xcl[96][65];
  __shared__ float xdbl[35][64];
  __shared__ float xw[35*96], cw[96*4], cbv[96], dwl[96*3], dbl[96];
  int bd = blockIdx.x >> 6, tile = blockIdx.x & 63;
  int dir = bd >> 1, b = bd & 1;
  int t0 = tile*64;
  int tid = threadIdx.x;
  const float* ip  = dir ? ip1  : ip0;
  const float* mw  = dir ? mw1  : mw0;
  const float* mb  = dir ? mb1  : mb0;
  const float* cwp = dir ? cwp1 : cwp0;
  const float* cbp = dir ? cbp1 : cbp0;
  const float* xpp = dir ? xpp1 : xpp0;
  const float* dwp = dir ? dwp1 : dwp0;
  const float* dbp = dir ? dbp1 : dbp0;
  for (int i = tid; i < 192*48; i += 256) Wl[i] = ip[i];
  for (int i = tid; i < 35*96;  i += 256) xw[i] = xpp[i];
  for (int i = tid; i < 96*4;   i += 256) cw[i] = cwp[i];
  for (int i = tid; i < 96*3;   i += 256) dwl[i] = dwp[i];
  for (int i = tid; i < 96;     i += 256){ cbv[i] = cbp[i]; dbl[i] = dbp[i]; }
  if (tid < 67){
    int r = tid;
    int tl = (r < 64) ? r + 3 : r - 64;
    int t = t0 - 3 + tl;
    if (t < 0){
      for (int c = 0; c < 48; c++) Vl[c][r] = 0.f;   // conv zero-pad
    } else {
      int h, w;
      if (dir == 0){ h = t >> 6; int wp = t & 63; w = (h & 1) ? 63 - wp : wp; }
      else         { w = t >> 6; int hp = t & 63; h = (w & 1) ? 63 - hp : hp; }
      int p = h*64 + w;
      const float* xb = x + (size_t)b*48*4096 + p;
      float v[48]; float mu = 0.f;
      #pragma unroll
      for (int c = 0; c < 48; c++){ v[c] = xb[c*4096]; mu += v[c]; }
      mu *= (1.f/48.f);
      float var = 0.f;
      #pragma unroll
      for (int c = 0; c < 48; c++){ float d0 = v[c]-mu; var += d0*d0; }
      float rs = rsqrtf(var*(1.f/48.f) + 1e-5f);
      float mu2 = 0.f;
      #pragma unroll
      for (int c = 0; c < 48; c++){
        float xn = (v[c]-mu)*rs*n1w[c] + n1b[c];
        int k = c >> 1;
        float ang = (float)t * __expf(-(float)(2*k) * (9.210340371976184f/48.f));
        float pe = (c & 1) ? cosf(ang) : sinf(ang);
        v[c] = xn + pe; mu2 += v[c];
      }
      mu2 *= (1.f/48.f);
      float var2 = 0.f;
      #pragma unroll
      for (int c = 0; c < 48; c++){ float d0 = v[c]-mu2; var2 += d0*d0; }
      float rs2 = rsqrtf(var2*(1.f/48.f) + 1e-5f);
      #pragma unroll
      for (int c = 0; c < 48; c++) Vl[c][r] = (v[c]-mu2)*rs2*mw[c] + mb[c];
    }
  }
  __syncthreads();
  // xm GEMV over 67 rows (incl. 3 boundary rows)
  for (int i = tid; i < 24*67; i += 256){
    int r = i % 67, jg = i / 67; int j0 = jg*4;
    float a0=0,a1=0,a2=0,a3=0;
    #pragma unroll 4
    for (int c = 0; c < 48; c++){
      float vv = Vl[c][r];
      a0 += vv*Wl[(j0+0)*48+c];
      a1 += vv*Wl[(j0+1)*48+c];
      a2 += vv*Wl[(j0+2)*48+c];
      a3 += vv*Wl[(j0+3)*48+c];
    }
    int tl = (r < 64) ? r + 3 : r - 64;
    xml[j0+0][tl]=a0; xml[j0+1][tl]=a1; xml[j0+2][tl]=a2; xml[j0+3][tl]=a3;
  }
  __syncthreads();
  // causal conv4 + silu
  for (int i = tid; i < 96*64; i += 256){
    int d = i >> 6, t = i & 63;
    float acc = cbv[d];
    #pragma unroll
    for (int k = 0; k < 4; k++) acc += cw[d*4+k]*xml[d][t+k];
    xcl[d][t] = siluf(acc);
  }
  __syncthreads();
  // z GEMV (overwrites xml — conv done) + xproj GEMV
  for (int i = tid; i < 24*64; i += 256){
    int r = i & 63, jg = i >> 6; int j0 = jg*4;
    float a0=0,a1=0,a2=0,a3=0;
    #pragma unroll 4
    for (int c = 0; c < 48; c++){
      float vv = Vl[c][r];
      a0 += vv*Wl[(96+j0+0)*48+c];
      a1 += vv*Wl[(96+j0+1)*48+c];
      a2 += vv*Wl[(96+j0+2)*48+c];
      a3 += vv*Wl[(96+j0+3)*48+c];
    }
    xml[j0+0][r]=a0; xml[j0+1][r]=a1; xml[j0+2][r]=a2; xml[j0+3][r]=a3;
  }
  for (int i = tid; i < 35*64; i += 256){
    int j = i >> 6, t = i & 63;
    float acc = 0.f;
    #pragma unroll 4
    for (int d = 0; d < 96; d++) acc += xcl[d][t]*xw[j*96+d];
    xdbl[j][t] = acc;
  }
  __syncthreads();
  // coalesced epilogue writes
  size_t gbase = (size_t)bd*4096 + t0;
  for (int i = tid; i < 64*96; i += 256){
    int t = i / 96, d = i % 96;
    xc[(gbase+t)*96 + d] = xcl[d][t];
    z [(gbase+t)*96 + d] = xml[d][t];
    float vdt = dbl[d];
    #pragma unroll
    for (int r3 = 0; r3 < 3; r3++) vdt += xdbl[r3][t]*dwl[d*3+r3];
    dt[(gbase+t)*96 + d] = softplusf(vdt);
  }
  for (int i = tid; i < 64*16; i += 256){
    int t = i / 16, s = i % 16;
    Bm[(gbase+t)*16+s] = xdbl[3+s][t];
    Cm[(gbase+t)*16+s] = xdbl[19+s][t];
  }
}

// ---------------- K3: chunk-local scan pass 1 (chunk=32).  Thread owns d, all 16 s in regs.
// 512 tasks (bd*128+ch); block = 192 threads = 2 tasks.
__global__ __launch_bounds__(192) void k3_scan1(const float* __restrict__ dtg,
    const float* __restrict__ xcg, const float* __restrict__ Bmg,
    const float* __restrict__ Alog0, const float* __restrict__ Alog1,
    float* __restrict__ P, float* __restrict__ S){
  __shared__ float dts[2][32][96], xcs[2][32][96];
  __shared__ alignas(16) float Bs[2][32][16];
  int tid = threadIdx.x;
  int task0 = blockIdx.x*2;
  for (int i = tid; i < 2*32*96; i += 192){
    int su = i / 3072, rem = i % 3072, t = rem / 96, dd = rem % 96;
    int task = task0 + su; int bd = task >> 7, ch = task & 127;
    size_t g = ((size_t)bd*4096 + ch*32 + t)*96 + dd;
    dts[su][t][dd] = dtg[g];
    xcs[su][t][dd] = xcg[g];
  }
  for (int i = tid; i < 2*32*16; i += 192){
    int su = i / 512, rem = i % 512, t = rem / 16, s = rem % 16;
    int task = task0 + su; int bd = task >> 7, ch = task & 127;
    Bs[su][t][s] = Bmg[((size_t)bd*4096 + ch*32 + t)*16 + s];
  }
  __syncthreads();
  int sub = tid / 96, d = tid % 96;
  int task = task0 + sub; int bd = task >> 7;
  const float* Alog = (bd >= 2) ? Alog1 : Alog0;
  float A[16], h[16], p[16];
  #pragma unroll
  for (int s = 0; s < 16; s++){ A[s] = -__expf(Alog[d*16+s]); h[s]=0.f; p[s]=1.f; }
  for (int t = 0; t < 32; t++){
    float dtd = dts[sub][t][d];
    float u = dtd * xcs[sub][t][d];
    const float4* Bp = (const float4*)&Bs[sub][t][0];
    float4 B0 = Bp[0], B1 = Bp[1], B2 = Bp[2], B3 = Bp[3];
    float bb[16] = {B0.x,B0.y,B0.z,B0.w, B1.x,B1.y,B1.z,B1.w,
                    B2.x,B2.y,B2.z,B2.w, B3.x,B3.y,B3.z,B3.w};
    #pragma unroll
    for (int s = 0; s < 16; s++){
      float a = __expf(dtd*A[s]);
      h[s] = a*h[s] + u*bb[s];
      p[s] *= a;
    }
  }
  size_t ob = (size_t)task*1536 + d*16;
  float4* Pp = (float4*)&P[ob];
  float4* Sp = (float4*)&S[ob];
  #pragma unroll
  for (int q = 0; q < 4; q++){
    Pp[q] = make_float4(p[4*q],p[4*q+1],p[4*q+2],p[4*q+3]);
    Sp[q] = make_float4(h[4*q],h[4*q+1],h[4*q+2],h[4*q+3]);
  }
}

// ---------------- K4: sequential chunk combine over 128 chunks.  24 blocks (4 bd x 6 groups).
__global__ __launch_bounds__(256) void k4_comb(const float* __restrict__ P,
    const float* __restrict__ S, float* __restrict__ Hin){
  int bd = blockIdx.x / 6, grp = blockIdx.x % 6;
  size_t idx = (size_t)bd*128*1536 + grp*256 + threadIdx.x;
  float h = 0.f;
  float p0 = P[idx], s0 = S[idx];
  float p1 = P[idx + 1536], s1 = S[idx + 1536];
  for (int c = 0; c < 128; c++){
    float pf = 0.f, sf = 0.f;
    if (c + 2 < 128){ pf = P[idx + (size_t)(c+2)*1536]; sf = S[idx + (size_t)(c+2)*1536]; }
    Hin[idx + (size_t)c*1536] = h;
    h = p0*h + s0;
    p0 = p1; s0 = s1; p1 = pf; s1 = sf;
  }
}

// ---------------- K5: pass-3 rescan + y = sum_s h*C (in-register) + gate, write yall.
__global__ __launch_bounds__(192) void k5_scan2(const float* __restrict__ dtg,
    const float* __restrict__ xcg, const float* __restrict__ Bmg, const float* __restrict__ Cmg,
    const float* __restrict__ Alog0, const float* __restrict__ Alog1,
    const float* __restrict__ Dp0, const float* __restrict__ Dp1,
    const float* __restrict__ zg, const float* __restrict__ Hin, float* __restrict__ yout){
  __shared__ float dts[2][32][96], xcs[2][32][96];
  __shared__ alignas(16) float Bs[2][32][16], Cs[2][32][16];
  int tid = threadIdx.x;
  int task0 = blockIdx.x*2;
  for (int i = tid; i < 2*32*96; i += 192){
    int su = i / 3072, rem = i % 3072, t = rem / 96, dd = rem % 96;
    int task = task0 + su; int bd = task >> 7, ch = task & 127;
    size_t g = ((size_t)bd*4096 + ch*32 + t)*96 + dd;
    dts[su][t][dd] = dtg[g];
    xcs[su][t][dd] = xcg[g];
  }
  for (int i = tid; i < 2*32*16; i += 192){
    int su = i / 512, rem = i % 512, t = rem / 16, s = rem % 16;
    int task = task0 + su; int bd = task >> 7, ch = task & 127;
    size_t g = ((size_t)bd*4096 + ch*32 + t)*16 + s;
    Bs[su][t][s] = Bmg[g];
    Cs[su][t][s] = Cmg[g];
  }
  __syncthreads();
  int sub = tid / 96, d = tid % 96;
  int task = task0 + sub; int bd = task >> 7, ch = task & 127;
  int t0g = ch*32;
  const float* Alog = (bd >= 2) ? Alog1 : Alog0;
  float Dd = ((bd >= 2) ? Dp1 : Dp0)[d];
  float A[16], h[16];
  #pragma unroll
  for (int s = 0; s < 16; s++) A[s] = -__expf(Alog[d*16+s]);
  {
    const float4* Hp = (const float4*)&Hin[(size_t)task*1536 + d*16];
    float4 H0 = Hp[0], H1 = Hp[1], H2 = Hp[2], H3 = Hp[3];
    h[0]=H0.x; h[1]=H0.y; h[2]=H0.z; h[3]=H0.w;
    h[4]=H1.x; h[5]=H1.y; h[6]=H1.z; h[7]=H1.w;
    h[8]=H2.x; h[9]=H2.y; h[10]=H2.z; h[11]=H2.w;
    h[12]=H3.x; h[13]=H3.y; h[14]=H3.z; h[15]=H3.w;
  }
  for (int t = 0; t < 32; t++){
    float dtd = dts[sub][t][d];
    float xcv = xcs[sub][t][d];
    float u = dtd * xcv;
    const float4* Bp = (const float4*)&Bs[sub][t][0];
    const float4* Cp = (const float4*)&Cs[sub][t][0];
    float4 B0 = Bp[0], B1 = Bp[1], B2 = Bp[2], B3 = Bp[3];
    float4 C0 = Cp[0], C1 = Cp[1], C2 = Cp[2], C3 = Cp[3];
    float bb[16] = {B0.x,B0.y,B0.z,B0.w, B1.x,B1.y,B1.z,B1.w,
                    B2.x,B2.y,B2.z,B2.w, B3.x,B3.y,B3.z,B3.w};
    float cc[16] = {C0.x,C0.y,C0.z,C0.w, C1.x,C1.y,C1.z,C1.w,
                    C2.x,C2.y,C2.z,C2.w, C3.x,C3.y,C3.z,C3.w};
    float y0=0,y1=0,y2=0,y3=0;
    #pragma unroll
    for (int s = 0; s < 16; s++){
      float a = __expf(dtd*A[s]);
      h[s] = a*h[s] + u*bb[s];
      float py = h[s]*cc[s];
      if ((s&3)==0) y0 += py; else if ((s&3)==1) y1 += py;
      else if ((s&3)==2) y2 += py; else y3 += py;
    }
    float y = (y0+y1)+(y2+y3);
    size_t gi = ((size_t)bd*4096 + t0g + t)*96 + d;
    float zv = zg[gi];
    yout[gi] = (y + xcv*Dd) * siluf(zv);
  }
}

// ---------------- K6: un-snake + outproj (96->48) both dirs + residual -> xmid
__global__ __launch_bounds__(256) void k6_outproj(const float* __restrict__ x,
    const float* __restrict__ y1, const float* __restrict__ y2,
    const float* __restrict__ op1, const float* __restrict__ op2, float* __restrict__ xmid){
  __shared__ float wl[48*96];
  __shared__ float ylds[64][97];
  int b = blockIdx.x >> 6, h = blockIdx.x & 63;
  int tid = threadIdx.x;
  float acc[3][4];
  #pragma unroll
  for (int a = 0; a < 3; a++) { acc[a][0]=0; acc[a][1]=0; acc[a][2]=0; acc[a][3]=0; }
  for (int pass = 0; pass < 2; pass++){
    __syncthreads();
    const float* op = pass ? op2 : op1;
    const float* y  = pass ? y2  : y1;
    for (int i = tid; i < 48*96; i += 256) wl[i] = op[i];
    if (pass == 0){
      for (int i = tid; i < 64*96; i += 256){
        int wp = i / 96, d = i % 96;
        int wsp = (h & 1) ? 63 - wp : wp;
        ylds[wsp][d] = y[((size_t)b*4096 + h*64 + wp)*96 + d];
      }
    } else {
      for (int i = tid; i < 64*96; i += 256){
        int w = i / 96, d = i % 96;
        int t = w*64 + ((w & 1) ? 63 - h : h);
        ylds[w][d] = y[((size_t)b*4096 + t)*96 + d];
      }
    }
    __syncthreads();
    for (int it = 0; it < 3; it++){
      int i = tid + it*256;
      int w = i & 63, cb = i >> 6;
      #pragma unroll 4
      for (int d = 0; d < 96; d++){
        float yv = ylds[w][d];
        #pragma unroll
        for (int q = 0; q < 4; q++) acc[it][q] += yv * wl[(cb*4+q)*96 + d];
      }
    }
  }
  for (int it = 0; it < 3; it++){
    int i = tid + it*256;
    int w = i & 63, cb = i >> 6;
    #pragma unroll
    for (int q = 0; q < 4; q++){
      int c = cb*4 + q;
      size_t idx = (((size_t)b*48 + c)*64 + h)*64 + w;
      xmid[idx] = x[idx] + acc[it][q];
    }
  }
}

// ---------------- K7: LN(n2) + 1x1 conv f_pin (48->192) -> xp (B,192,H,W)
__global__ __launch_bounds__(256) void k7_ln_pin(const float* __restrict__ xmid,
    const float* __restrict__ nw, const float* __restrict__ nb,
    const float* __restrict__ pin, float* __restrict__ xp){
  __shared__ float wl[192*48];
  __shared__ float xl[48][64];
  int b = blockIdx.x >> 6, h = blockIdx.x & 63;
  int tid = threadIdx.x;
  for (int i = tid; i < 192*48; i += 256) wl[i] = pin[i];
  if (tid < 64){
    int w = tid;
    float v[48]; float mu = 0.f;
    #pragma unroll
    for (int c = 0; c < 48; c++){ v[c] = xmid[(((size_t)b*48+c)*64 + h)*64 + w]; mu += v[c]; }
    mu *= (1.f/48.f);
    float var = 0.f;
    #pragma unroll
    for (int c = 0; c < 48; c++){ float d = v[c]-mu; var += d*d; }
    var *= (1.f/48.f);
    float rs = rsqrtf(var + 1e-5f);
    #pragma unroll
    for (int c = 0; c < 48; c++) xl[c][w] = (v[c]-mu)*rs*nw[c] + nb[c];
  }
  __syncthreads();
  for (int i = tid; i < 48*64; i += 256){
    int w = i & 63, ob = i >> 6; int o0 = ob*4;
    float a0=0,a1=0,a2=0,a3=0;
    #pragma unroll 4
    for (int c = 0; c < 48; c++){
      float xv = xl[c][w];
      a0 += xv*wl[(o0+0)*48+c];
      a1 += xv*wl[(o0+1)*48+c];
      a2 += xv*wl[(o0+2)*48+c];
      a3 += xv*wl[(o0+3)*48+c];
    }
    xp[(((size_t)b*192 + o0+0)*64 + h)*64 + w] = a0;
    xp[(((size_t)b*192 + o0+1)*64 + h)*64 + w] = a1;
    xp[(((size_t)b*192 + o0+2)*64 + h)*64 + w] = a2;
    xp[(((size_t)b*192 + o0+3)*64 + h)*64 + w] = a3;
  }
}

// ---------------- K8: 2x2 avg pool of original x -> (B,48,32,32)
__global__ __launch_bounds__(256) void k8_pool(const float* __restrict__ x, float* __restrict__ yp){
  int idx = blockIdx.x*256 + threadIdx.x;
  if (idx >= 2*48*32*32) return;
  int j = idx & 31, i = (idx >> 5) & 31, c = (idx >> 10) % 48, b = idx / (48*1024);
  const float* xb = x + (((size_t)b*48 + c)*64 + 2*i)*64 + 2*j;
  yp[idx] = 0.25f*(xb[0] + xb[1] + xb[64] + xb[65]);
}

// ---------------- K9: direct 3x3 conv 48->48 on 32x32
__global__ __launch_bounds__(256) void k9_conv3(const float* __restrict__ in,
    const float* __restrict__ wgt, const float* __restrict__ bias, float* __restrict__ out){
  __shared__ float sin_[48][3][34];
  __shared__ float wl[24*48*9];
  int bid = blockIdx.x;
  int coh = bid & 1, i0 = (bid >> 1) & 31, b = bid >> 6;
  int tid = threadIdx.x;
  for (int i = tid; i < 24*48*9; i += 256) wl[i] = wgt[coh*24*48*9 + i];
  for (int i = tid; i < 48*3*34; i += 256){
    int jx = i % 34, ky = (i/34) % 3, ci = i/(34*3);
    int r = i0 + ky - 1, j = jx - 1;
    float v = 0.f;
    if (r >= 0 && r < 32 && j >= 0 && j < 32)
      v = in[(((size_t)b*48 + ci)*32 + r)*32 + j];
    sin_[ci][ky][jx] = v;
  }
  __syncthreads();
  for (int i = tid; i < 24*32; i += 256){
    int j = i & 31, col = i >> 5;
    float acc = bias[coh*24 + col];
    for (int ci = 0; ci < 48; ci++){
      const float* wp = wl + ((size_t)col*48 + ci)*9;
      #pragma unroll
      for (int ky = 0; ky < 3; ky++)
        #pragma unroll
        for (int kx = 0; kx < 3; kx++)
          acc += sin_[ci][ky][j+kx] * wp[ky*3+kx];
    }
    out[(((size_t)b*48 + coh*24 + col)*32 + i0)*32 + j] = acc;
  }
}

// ---------------- K10: LN over C + relu on (B,48,32,32)
__global__ __launch_bounds__(256) void k10_lnrelu(const float* __restrict__ in,
    const float* __restrict__ w, const float* __restrict__ bia, float* __restrict__ out){
  int idx = blockIdx.x*256 + threadIdx.x;
  if (idx >= 2*1024) return;
  int b = idx >> 10, p = idx & 1023;
  const float* ip = in + (size_t)b*48*1024 + p;
  float v[48]; float mu = 0.f;
  #pragma unroll
  for (int c = 0; c < 48; c++){ v[c] = ip[c*1024]; mu += v[c]; }
  mu *= (1.f/48.f);
  float var = 0.f;
  #pragma unroll
  for (int c = 0; c < 48; c++){ float d = v[c]-mu; var += d*d; }
  var *= (1.f/48.f);
  float rs = rsqrtf(var + 1e-5f);
  float* op = out + (size_t)b*48*1024 + p;
  #pragma unroll
  for (int c = 0; c < 48; c++){
    float t = (v[c]-mu)*rs*w[c] + bia[c];
    op[c*1024] = fmaxf(t, 0.f);
  }
}

// ---------------- K13: depthwise 3x3, pad 1, CH channels, 64x64
__global__ __launch_bounds__(256) void k13_dw(const float* __restrict__ in,
    const float* __restrict__ wgt, float* __restrict__ out, int CH){
  int idx = blockIdx.x*256 + threadIdx.x;
  if (idx >= 2*CH*4096) return;
  int w = idx & 63, h = (idx >> 6) & 63, c = (idx >> 12) % CH, b = idx / (CH*4096);
  const float* ip = in + ((size_t)b*CH + c)*4096;
  const float* wp = wgt + c*9;
  float acc = 0.f;
  #pragma unroll
  for (int ky = 0; ky < 3; ky++){
    int hh = h + ky - 1;
    if (hh < 0 || hh > 63) continue;
    #pragma unroll
    for (int kx = 0; kx < 3; kx++){
      int ww = w + kx - 1;
      if (ww < 0 || ww > 63) continue;
      acc += wp[ky*3+kx] * ip[hh*64 + ww];
    }
  }
  out[idx] = acc;
}

// ---------------- K14: 1x1 conv f_fus over concat(xd[:96], upsample(yb)) -> x1 (96 ch)
__global__ __launch_bounds__(256) void k14_fus(const float* __restrict__ xd,
    const float* __restrict__ yb, const float* __restrict__ fus, float* __restrict__ x1){
  __shared__ float wl[48*144];
  __shared__ float al[96][64];
  __shared__ float yl[48][32];
  int bid = blockIdx.x;
  int oh = bid & 1, h = (bid >> 1) & 63, b = bid >> 7;
  int tid = threadIdx.x;
  for (int i = tid; i < 48*144; i += 256) wl[i] = fus[(size_t)oh*48*144 + i];
  for (int i = tid; i < 96*64; i += 256){
    int ci = i >> 6, w = i & 63;
    al[ci][w] = xd[(((size_t)b*192 + ci)*64 + h)*64 + w];
  }
  for (int i = tid; i < 48*32; i += 256){
    int cj = i >> 5, j = i & 31;
    yl[cj][j] = yb[(((size_t)b*48 + cj)*32 + (h >> 1))*32 + j];
  }
  __syncthreads();
  for (int it = 0; it < 3; it++){
    int i = tid + it*256;
    int w = i & 63, ob = i >> 6; int o0 = ob*4;
    float a[4] = {0,0,0,0};
    #pragma unroll 4
    for (int ci = 0; ci < 96; ci++){
      float xv = al[ci][w];
      #pragma unroll
      for (int q = 0; q < 4; q++) a[q] += xv * wl[(o0+q)*144 + ci];
    }
    int w2 = w >> 1;
    #pragma unroll 4
    for (int cj = 0; cj < 48; cj++){
      float yv = yl[cj][w2];
      #pragma unroll
      for (int q = 0; q < 4; q++) a[q] += yv * wl[(o0+q)*144 + 96 + cj];
    }
    #pragma unroll
    for (int q = 0; q < 4; q++)
      x1[(((size_t)b*96 + oh*48 + o0 + q)*64 + h)*64 + w] = a[q];
  }
}

// ---------------- K16: gelu(x1d)*x2 -> 1x1 conv f_pout (96->48) -> + xmid -> out
__global__ __launch_bounds__(256) void k16_out(const float* __restrict__ x1d,
    const float* __restrict__ xd, const float* __restrict__ pout,
    const float* __restrict__ xmid, float* __restrict__ out){
  __shared__ float wl[48*96];
  __shared__ float gl[96][64];
  int b = blockIdx.x >> 6, h = blockIdx.x & 63;
  int tid = threadIdx.x;
  for (int i = tid; i < 48*96; i += 256) wl[i] = pout[i];
  for (int i = tid; i < 96*64; i += 256){
    int ch = i >> 6, w = i & 63;
    float a  = x1d[(((size_t)b*96 + ch)*64 + h)*64 + w];
    float x2 = xd[(((size_t)b*192 + 96 + ch)*64 + h)*64 + w];
    gl[ch][w] = geluf(a) * x2;
  }
  __syncthreads();
  for (int it = 0; it < 3; it++){
    int i = tid + it*256;
    int w = i & 63, cbk = i >> 6; int c0 = cbk*4;
    float a[4] = {0,0,0,0};
    #pragma unroll 4
    for (int ch = 0; ch < 96; ch++){
      float gv = gl[ch][w];
      #pragma unroll
      for (int q = 0; q < 4; q++) a[q] += gv * wl[(c0+q)*96 + ch];
    }
    #pragma unroll
    for (int q = 0; q < 4; q++){
      size_t idx = (((size_t)b*48 + c0 + q)*64 + h)*64 + w;
      out[idx] = xmid[idx] + a[q];
    }
  }
}

extern "C" void kernel_launch(void* const* d_in, const int* in_sizes, int n_in,
                              void* d_out, int out_size, void* d_ws, size_t ws_size,
                              hipStream_t stream){
  (void)in_sizes; (void)n_in; (void)out_size; (void)ws_size;
  const float* x    = (const float*)d_in[0];
  const float* n1w  = (const float*)d_in[1];
  const float* n1b  = (const float*)d_in[2];
  const float* n2w  = (const float*)d_in[3];
  const float* n2b  = (const float*)d_in[4];
  const float* mlnw[2] = {(const float*)d_in[5], (const float*)d_in[7]};
  const float* mlnb[2] = {(const float*)d_in[6], (const float*)d_in[8]};
  const float* fln1w = (const float*)d_in[9];
  const float* fln1b = (const float*)d_in[10];
  const float* fln2w = (const float*)d_in[11];
  const float* fln2b = (const float*)d_in[12];
  const float* inproj[2]  = {(const float*)d_in[13], (const float*)d_in[22]};
  const float* convw[2]   = {(const float*)d_in[14], (const float*)d_in[23]};
  const float* convb[2]   = {(const float*)d_in[15], (const float*)d_in[24]};
  const float* xproj[2]   = {(const float*)d_in[16], (const float*)d_in[25]};
  const float* dtw[2]     = {(const float*)d_in[17], (const float*)d_in[26]};
  const float* dtbp[2]    = {(const float*)d_in[18], (const float*)d_in[27]};
  const float* Alog[2]    = {(const float*)d_in[19], (const float*)d_in[28]};
  const float* Dp[2]      = {(const float*)d_in[20], (const float*)d_in[29]};
  const float* outproj[2] = {(const float*)d_in[21], (const float*)d_in[30]};
  const float* fpin  = (const float*)d_in[31];
  const float* fdw   = (const float*)d_in[32];
  const float* ffus  = (const float*)d_in[33];
  const float* fdwa  = (const float*)d_in[34];
  const float* fpout = (const float*)d_in[35];
  const float* fc1w  = (const float*)d_in[36];
  const float* fc1b  = (const float*)d_in[37];
  const float* fc2w  = (const float*)d_in[38];
  const float* fc2b  = (const float*)d_in[39];

  // workspace layout (floats); bd = dir*2+b indexes the 4 mamba sequences
  float* ws = (float*)d_ws;
  float* zb   = ws + 0;         // (4,4096,96) = 1572864   -> later xpb (B,192,64,64)
  float* xcb  = ws + 1572864;   // (4,4096,96)             -> later xdb (B,192,64,64)
  float* dtb  = ws + 3145728;   // (4,4096,96)             -> later x1b + x1db
  float* Bmb  = ws + 4718592;   // (4,4096,16) = 262144
  float* Cmb  = ws + 4980736;   // (4,4096,16)
  float* Pb   = ws + 5242880;   // (512,1536) = 786432     -> later yall dir0 (y1)
  float* Sb   = ws + 6029312;   // (512,1536)              -> later yall dir1 (y2)
  float* Hb   = ws + 6815744;   // (512,1536)              -> later pool chain
  float* xmid = ws + 7602176;   // (B,48,64,64) = 393216   [total 7995392 floats = 32.0 MB]
  float* yall = Pb;             // (4,4096,96) spans Pb..Sb
  float* xpb  = zb;
  float* xdb  = xcb;
  float* x1b  = dtb;
  float* x1db = dtb + 786432;
  float* ypb  = Hb;
  float* ta   = Hb + 98304;
  float* tbuf = Hb + 196608;
  float* ybb  = Hb + 294912;

  k12_fused<<<256,256,0,stream>>>(x, n1w, n1b,
      mlnw[0], mlnb[0], mlnw[1], mlnb[1],
      inproj[0], inproj[1], convw[0], convw[1], convb[0], convb[1],
      xproj[0], xproj[1], dtw[0], dtw[1], dtbp[0], dtbp[1],
      xcb, dtb, Bmb, Cmb, zb);
  k3_scan1 <<<256,192,0,stream>>>(dtb, xcb, Bmb, Alog[0], Alog[1], Pb, Sb);
  k4_comb  <<<24,256,0,stream>>>(Pb, Sb, Hb);
  k5_scan2 <<<256,192,0,stream>>>(dtb, xcb, Bmb, Cmb, Alog[0], Alog[1],
                                  Dp[0], Dp[1], zb, Hb, yall);
  k6_outproj<<<128,256,0,stream>>>(x, yall, yall + 786432, outproj[0], outproj[1], xmid);
  k7_ln_pin <<<128,256,0,stream>>>(xmid, n2w, n2b, fpin, xpb);
  k8_pool   <<<384,256,0,stream>>>(x, ypb);
  k9_conv3  <<<128,256,0,stream>>>(ypb, fc1w, fc1b, ta);
  k10_lnrelu<<<8,256,0,stream>>>(ta, fln1w, fln1b, tbuf);
  k9_conv3  <<<128,256,0,stream>>>(tbuf, fc2w, fc2b, ta);
  k10_lnrelu<<<8,256,0,stream>>>(ta, fln2w, fln2b, ybb);
  k13_dw    <<<6144,256,0,stream>>>(xpb, fdw, xdb, 192);
  k14_fus   <<<256,256,0,stream>>>(xdb, ybb, ffus, x1b);
  k13_dw    <<<3072,256,0,stream>>>(x1b, fdwa, x1db, 96);
  k16_out   <<<128,256,0,stream>>>(x1db, xdb, fpout, xmid, (float*)d_out);
}

// Round 4
// 264.528 us; speedup vs baseline: 1.9875x; 1.0361x over previous
//
#include <hip/hip_runtime.h>

// SBSM block: B=2, C=48, H=W=64, L=4096, DI=96, DS=16, DCONV=4, DTR=3, HF=96
#define DEV __device__ __forceinline__

DEV float siluf(float x){ return x / (1.f + __expf(-x)); }
DEV float softplusf(float x){ return fmaxf(x, 0.f) + log1pf(expf(-fabsf(x))); }
DEV float geluf(float x){ return 0.5f * x * (1.f + erff(x * 0.70710678118654752440f)); }

// ---------------- kA: snake gather + LN(n1) + posenc + LN(mln) -> Vg(48) ; inproj xm-half -> xmg(96)
// grid: 4 bd x 128 tiles(32) = 512 blocks x 256 thr.  LDS ~26 KB.
__global__ __launch_bounds__(256) void kA_front(const float* __restrict__ x,
    const float* __restrict__ n1w, const float* __restrict__ n1b,
    const float* __restrict__ mw0, const float* __restrict__ mb0,
    const float* __restrict__ mw1, const float* __restrict__ mb1,
    const float* __restrict__ ip0, const float* __restrict__ ip1,
    float* __restrict__ xmg, float* __restrict__ Vg){
  __shared__ alignas(16) float Vl[48*36];   // [c][r], pad 36
  __shared__ float Wt[48*97];               // transposed inproj xm-half: Wt[c][j]
  __shared__ float mu_s[32], rs_s[32];
  int bd = blockIdx.x >> 7, tile = blockIdx.x & 127;
  int dir = bd >> 1, b = bd & 1;
  int t0 = tile*32;
  int tid = threadIdx.x;
  const float* ip = dir ? ip1 : ip0;
  const float* mw = dir ? mw1 : mw0;
  const float* mb = dir ? mb1 : mb0;
  // stage transposed weights (xm half: rows 0..95)
  for (int i = tid; i < 96*48; i += 256){
    int j = i / 48, c = i % 48;
    Wt[c*97 + j] = ip[i];
  }
  // stage x (snake order)
  for (int i = tid; i < 48*32; i += 256){
    int c = i >> 5, r = i & 31;
    int t = t0 + r;
    int h, w;
    if (dir == 0){ h = t >> 6; int wp = t & 63; w = (h & 1) ? 63 - wp : wp; }
    else         { w = t >> 6; int hp = t & 63; h = (w & 1) ? 63 - hp : hp; }
    Vl[c*36 + r] = x[(size_t)b*48*4096 + c*4096 + h*64 + w];
  }
  __syncthreads();
  // stats round 1 (8 lanes per row)
  {
    int r = tid >> 3, k = tid & 7;
    float s1 = 0.f, s2 = 0.f;
    #pragma unroll
    for (int cc = 0; cc < 6; cc++){
      float v = Vl[(k*6+cc)*36 + r];
      s1 += v; s2 += v*v;
    }
    s1 += __shfl_xor(s1,1); s2 += __shfl_xor(s2,1);
    s1 += __shfl_xor(s1,2); s2 += __shfl_xor(s2,2);
    s1 += __shfl_xor(s1,4); s2 += __shfl_xor(s2,4);
    if (k == 0){
      float m = s1*(1.f/48.f);
      mu_s[r] = m;
      rs_s[r] = rsqrtf(s2*(1.f/48.f) - m*m + 1e-5f);
    }
  }
  __syncthreads();
  // apply LN1 + posenc
  for (int i = tid; i < 48*32; i += 256){
    int c = i >> 5, r = i & 31;
    int t = t0 + r;
    float v = Vl[c*36 + r];
    float xn = (v - mu_s[r])*rs_s[r]*n1w[c] + n1b[c];
    float ang = (float)t * expf(-(float)(c & ~1) * (9.210340371976184f/48.f));
    float pe = (c & 1) ? cosf(ang) : sinf(ang);
    Vl[c*36 + r] = xn + pe;
  }
  __syncthreads();
  // stats round 2
  {
    int r = tid >> 3, k = tid & 7;
    float s1 = 0.f, s2 = 0.f;
    #pragma unroll
    for (int cc = 0; cc < 6; cc++){
      float v = Vl[(k*6+cc)*36 + r];
      s1 += v; s2 += v*v;
    }
    s1 += __shfl_xor(s1,1); s2 += __shfl_xor(s2,1);
    s1 += __shfl_xor(s1,2); s2 += __shfl_xor(s2,2);
    s1 += __shfl_xor(s1,4); s2 += __shfl_xor(s2,4);
    if (k == 0){
      float m = s1*(1.f/48.f);
      mu_s[r] = m;
      rs_s[r] = rsqrtf(s2*(1.f/48.f) - m*m + 1e-5f);
    }
  }
  __syncthreads();
  // apply LN2 (mln), write Vg coalesced
  for (int i = tid; i < 32*48; i += 256){
    int r = i / 48, c = i % 48;
    float v = Vl[c*36 + r];
    float v2 = (v - mu_s[r])*rs_s[r]*mw[c] + mb[c];
    Vl[c*36 + r] = v2;
    Vg[((size_t)bd*4096 + t0 + r)*48 + c] = v2;
  }
  __syncthreads();
  // xm GEMV: tasks (j 0..95, rb 0..7), 4 r per task via float4
  for (int k = 0; k < 3; k++){
    int i = tid + k*256;
    int j = i % 96, rb = i / 96;
    float a0=0.f, a1=0.f, a2=0.f, a3=0.f;
    #pragma unroll 4
    for (int c = 0; c < 48; c++){
      float wv = Wt[c*97 + j];
      const float4 v4 = *(const float4*)&Vl[c*36 + rb*4];
      a0 += wv*v4.x; a1 += wv*v4.y; a2 += wv*v4.z; a3 += wv*v4.w;
    }
    size_t g = ((size_t)bd*4096 + t0 + rb*4)*96 + j;
    xmg[g] = a0; xmg[g+96] = a1; xmg[g+192] = a2; xmg[g+288] = a3;
  }
}

// ---------------- kB: causal conv4+silu + xproj + dt/B/C + scan pass-1 (chunk=32)
// grid: 512 blocks (bd x 128 tiles) x 384 thr.  LDS ~65 KB -> 2 blocks/CU.
__global__ __launch_bounds__(384) void kB_convscan(const float* __restrict__ xmg,
    const float* __restrict__ cwp0, const float* __restrict__ cwp1,
    const float* __restrict__ cbp0, const float* __restrict__ cbp1,
    const float* __restrict__ xpp0, const float* __restrict__ xpp1,
    const float* __restrict__ dwp0, const float* __restrict__ dwp1,
    const float* __restrict__ dbp0, const float* __restrict__ dbp1,
    const float* __restrict__ Alog0, const float* __restrict__ Alog1,
    float* __restrict__ xcg, float* __restrict__ dtg,
    float* __restrict__ Bmg, float* __restrict__ Cmg,
    float* __restrict__ P, float* __restrict__ S){
  __shared__ float xml[96*36];   // [d][tl], tl 0..34 (3 halo)
  __shared__ float xcl[96*33];   // [d][t]
  __shared__ float dtl[96*33];
  __shared__ float xwl[35*96];
  __shared__ float xdbl[35*33];
  __shared__ alignas(16) float Bl[32*16], Cl[32*16];
  __shared__ float cw[96*4], cbv[96], dwl[96*3], dbl[96];
  int bd = blockIdx.x >> 7, tile = blockIdx.x & 127;
  int dir = bd >> 1;
  int t0 = tile*32;
  int tid = threadIdx.x;
  const float* cwp = dir ? cwp1 : cwp0;
  const float* cbp = dir ? cbp1 : cbp0;
  const float* xpp = dir ? xpp1 : xpp0;
  const float* dwp = dir ? dwp1 : dwp0;
  const float* dbp = dir ? dbp1 : dbp0;
  const float* Alog = dir ? Alog1 : Alog0;
  // stage xm tile + 3-row halo
  for (int i = tid; i < 35*96; i += 384){
    int tl = i / 96, d = i % 96;
    int t = t0 - 3 + tl;
    xml[d*36 + tl] = (t >= 0) ? xmg[((size_t)bd*4096 + t)*96 + d] : 0.f;
  }
  for (int i = tid; i < 35*96; i += 384) xwl[i] = xpp[i];
  for (int i = tid; i < 96*4;  i += 384) cw[i] = cwp[i];
  for (int i = tid; i < 96*3;  i += 384) dwl[i] = dwp[i];
  for (int i = tid; i < 96;    i += 384){ cbv[i] = cbp[i]; dbl[i] = dbp[i]; }
  __syncthreads();
  // conv4 + silu
  for (int i = tid; i < 96*32; i += 384){
    int d = i >> 5, t = i & 31;
    float acc = cbv[d];
    #pragma unroll
    for (int k = 0; k < 4; k++) acc += cw[d*4+k]*xml[d*36 + t + k];
    xcl[d*33 + t] = siluf(acc);
  }
  __syncthreads();
  // xproj (96 -> 35)
  for (int i = tid; i < 35*32; i += 384){
    int j = i / 32, t = i % 32;
    float acc = 0.f;
    #pragma unroll 4
    for (int d = 0; d < 96; d++) acc += xcl[d*33 + t]*xwl[j*96 + d];
    xdbl[j*33 + t] = acc;
  }
  __syncthreads();
  // dt = softplus(xdbl[0:3] @ dtw + dtb);  B/C split
  for (int i = tid; i < 96*32; i += 384){
    int d = i >> 5, t = i & 31;
    float v = dbl[d];
    #pragma unroll
    for (int r = 0; r < 3; r++) v += xdbl[r*33 + t]*dwl[d*3 + r];
    dtl[d*33 + t] = softplusf(v);
  }
  for (int i = tid; i < 32*16; i += 384){
    int t = i / 16, s = i % 16;
    Bl[t*16 + s] = xdbl[(3+s)*33 + t];
    Cl[t*16 + s] = xdbl[(19+s)*33 + t];
  }
  __syncthreads();
  // global epilogue writes (coalesced)
  for (int i = tid; i < 32*96; i += 384){
    int t = i / 96, d = i % 96;
    size_t g = ((size_t)bd*4096 + t0 + t)*96 + d;
    xcg[g] = xcl[d*33 + t];
    dtg[g] = dtl[d*33 + t];
  }
  for (int i = tid; i < 32*16; i += 384){
    int t = i / 16, s = i % 16;
    size_t g = ((size_t)bd*4096 + t0 + t)*16 + s;
    Bmg[g] = Bl[t*16 + s];
    Cmg[g] = Cl[t*16 + s];
  }
  // scan pass 1: thread owns (d, s-quad)
  {
    int d = tid >> 2, q = tid & 3;
    float A0 = -__expf(Alog[d*16 + q*4 + 0]);
    float A1 = -__expf(Alog[d*16 + q*4 + 1]);
    float A2 = -__expf(Alog[d*16 + q*4 + 2]);
    float A3 = -__expf(Alog[d*16 + q*4 + 3]);
    float h0=0.f,h1=0.f,h2=0.f,h3=0.f, p0=1.f,p1=1.f,p2=1.f,p3=1.f;
    for (int t = 0; t < 32; t++){
      float dtd = dtl[d*33 + t];
      float u = dtd * xcl[d*33 + t];
      const float4 b4 = *(const float4*)&Bl[t*16 + q*4];
      float a0 = __expf(dtd*A0), a1 = __expf(dtd*A1), a2 = __expf(dtd*A2), a3 = __expf(dtd*A3);
      h0 = a0*h0 + u*b4.x; p0 *= a0;
      h1 = a1*h1 + u*b4.y; p1 *= a1;
      h2 = a2*h2 + u*b4.z; p2 *= a2;
      h3 = a3*h3 + u*b4.w; p3 *= a3;
    }
    size_t ob = (size_t)blockIdx.x*1536 + d*16 + q*4;
    *(float4*)&P[ob] = make_float4(p0,p1,p2,p3);
    *(float4*)&S[ob] = make_float4(h0,h1,h2,h3);
  }
}

// ---------------- k4: sequential chunk combine over 128 chunks, IN PLACE (Hin = P).
__global__ __launch_bounds__(256) void k4_comb(float* __restrict__ P, const float* __restrict__ S){
  int tid2 = blockIdx.x*256 + threadIdx.x;   // 6144 lanes
  int bd = tid2 / 1536, r = tid2 % 1536;
  size_t idx = (size_t)bd*128*1536 + r;
  const int ST = 1536;
  float pb0,pb1,pb2,pb3,pb4,pb5,pb6,pb7, sb0,sb1,sb2,sb3,sb4,sb5,sb6,sb7;
  pb0=P[idx+0*ST]; sb0=S[idx+0*ST]; pb1=P[idx+1*ST]; sb1=S[idx+1*ST];
  pb2=P[idx+2*ST]; sb2=S[idx+2*ST]; pb3=P[idx+3*ST]; sb3=S[idx+3*ST];
  pb4=P[idx+4*ST]; sb4=S[idx+4*ST]; pb5=P[idx+5*ST]; sb5=S[idx+5*ST];
  pb6=P[idx+6*ST]; sb6=S[idx+6*ST]; pb7=P[idx+7*ST]; sb7=S[idx+7*ST];
  float h = 0.f;
  for (int c0 = 0; c0 < 128; c0 += 8){
    float pn0=0,sn0=0,pn1=0,sn1=0,pn2=0,sn2=0,pn3=0,sn3=0;
    float pn4=0,sn4=0,pn5=0,sn5=0,pn6=0,sn6=0,pn7=0,sn7=0;
    if (c0 + 8 < 128){
      pn0=P[idx+(size_t)(c0+8)*ST];  sn0=S[idx+(size_t)(c0+8)*ST];
      pn1=P[idx+(size_t)(c0+9)*ST];  sn1=S[idx+(size_t)(c0+9)*ST];
      pn2=P[idx+(size_t)(c0+10)*ST]; sn2=S[idx+(size_t)(c0+10)*ST];
      pn3=P[idx+(size_t)(c0+11)*ST]; sn3=S[idx+(size_t)(c0+11)*ST];
      pn4=P[idx+(size_t)(c0+12)*ST]; sn4=S[idx+(size_t)(c0+12)*ST];
      pn5=P[idx+(size_t)(c0+13)*ST]; sn5=S[idx+(size_t)(c0+13)*ST];
      pn6=P[idx+(size_t)(c0+14)*ST]; sn6=S[idx+(size_t)(c0+14)*ST];
      pn7=P[idx+(size_t)(c0+15)*ST]; sn7=S[idx+(size_t)(c0+15)*ST];
    }
    P[idx+(size_t)(c0+0)*ST] = h; h = pb0*h + sb0;
    P[idx+(size_t)(c0+1)*ST] = h; h = pb1*h + sb1;
    P[idx+(size_t)(c0+2)*ST] = h; h = pb2*h + sb2;
    P[idx+(size_t)(c0+3)*ST] = h; h = pb3*h + sb3;
    P[idx+(size_t)(c0+4)*ST] = h; h = pb4*h + sb4;
    P[idx+(size_t)(c0+5)*ST] = h; h = pb5*h + sb5;
    P[idx+(size_t)(c0+6)*ST] = h; h = pb6*h + sb6;
    P[idx+(size_t)(c0+7)*ST] = h; h = pb7*h + sb7;
    pb0=pn0;sb0=sn0;pb1=pn1;sb1=sn1;pb2=pn2;sb2=sn2;pb3=pn3;sb3=sn3;
    pb4=pn4;sb4=sn4;pb5=pn5;sb5=sn5;pb6=pn6;sb6=sn6;pb7=pn7;sb7=sn7;
  }
}

// ---------------- k5: pass-3 rescan + y=sum_s h*C + z GEMV + gate -> yall
// grid: 512 blocks (task = bd*128+ch) x 384 thr.
__global__ __launch_bounds__(384) void k5_scan2(const float* __restrict__ dtg,
    const float* __restrict__ xcg, const float* __restrict__ Bmg, const float* __restrict__ Cmg,
    const float* __restrict__ Alog0, const float* __restrict__ Alog1,
    const float* __restrict__ Dp0, const float* __restrict__ Dp1,
    const float* __restrict__ ip0, const float* __restrict__ ip1,
    const float* __restrict__ Vg, const float* __restrict__ Hin, float* __restrict__ yout){
  __shared__ float dts[32*96], xcs[32*96];
  __shared__ alignas(16) float Bl[32*16], Cl[32*16];
  __shared__ float yl[32*96];
  __shared__ float Wzt[48*97];    // transposed z-half of inproj
  __shared__ float Vgs[32*48];
  int task = blockIdx.x;
  int bd = task >> 7, ch = task & 127;
  int t0 = ch*32;
  int tid = threadIdx.x;
  const float* ip   = (bd >= 2) ? ip1 : ip0;
  const float* Alog = (bd >= 2) ? Alog1 : Alog0;
  const float* Dp   = (bd >= 2) ? Dp1 : Dp0;
  for (int i = tid; i < 32*96; i += 384){
    int t = i / 96, d = i % 96;
    size_t g = ((size_t)bd*4096 + t0 + t)*96 + d;
    dts[t*96 + d] = dtg[g];
    xcs[t*96 + d] = xcg[g];
  }
  for (int i = tid; i < 32*16; i += 384){
    int t = i / 16, s = i % 16;
    size_t g = ((size_t)bd*4096 + t0 + t)*16 + s;
    Bl[t*16 + s] = Bmg[g];
    Cl[t*16 + s] = Cmg[g];
  }
  for (int i = tid; i < 96*48; i += 384){
    int j = i / 48, c = i % 48;
    Wzt[c*97 + j] = ip[(96 + j)*48 + c];
  }
  for (int i = tid; i < 32*48; i += 384){
    int t = i / 48, c = i % 48;
    Vgs[t*48 + c] = Vg[((size_t)bd*4096 + t0 + t)*48 + c];
  }
  __syncthreads();
  // rescan
  {
    int d = tid >> 2, q = tid & 3;
    float A0 = -__expf(Alog[d*16 + q*4 + 0]);
    float A1 = -__expf(Alog[d*16 + q*4 + 1]);
    float A2 = -__expf(Alog[d*16 + q*4 + 2]);
    float A3 = -__expf(Alog[d*16 + q*4 + 3]);
    const float4 h4 = *(const float4*)&Hin[(size_t)task*1536 + d*16 + q*4];
    float h0 = h4.x, h1 = h4.y, h2 = h4.z, h3 = h4.w;
    for (int t = 0; t < 32; t++){
      float dtd = dts[t*96 + d];
      float u = dtd * xcs[t*96 + d];
      const float4 b4 = *(const float4*)&Bl[t*16 + q*4];
      const float4 c4 = *(const float4*)&Cl[t*16 + q*4];
      float a0 = __expf(dtd*A0), a1 = __expf(dtd*A1), a2 = __expf(dtd*A2), a3 = __expf(dtd*A3);
      h0 = a0*h0 + u*b4.x;
      h1 = a1*h1 + u*b4.y;
      h2 = a2*h2 + u*b4.z;
      h3 = a3*h3 + u*b4.w;
      float py = (h0*c4.x + h1*c4.y) + (h2*c4.z + h3*c4.w);
      py += __shfl_xor(py, 1);
      py += __shfl_xor(py, 2);
      if (q == 0) yl[t*96 + d] = py;
    }
  }
  __syncthreads();
  // epilogue: z GEMV (48 -> 96) + D-term + silu gate
  for (int i = tid; i < 32*96; i += 384){
    int t = i / 96, d = i % 96;
    float z = 0.f;
    #pragma unroll 4
    for (int c = 0; c < 48; c++) z += Wzt[c*97 + d] * Vgs[t*48 + c];
    float xcv = xcs[t*96 + d];
    float y = yl[t*96 + d] + xcv*Dp[d];
    size_t g = ((size_t)bd*4096 + t0 + t)*96 + d;
    yout[g] = y * siluf(z);
  }
}

// ---------------- K6: un-snake + outproj (96->48) both dirs + residual -> xmid
__global__ __launch_bounds__(256) void k6_outproj(const float* __restrict__ x,
    const float* __restrict__ y1, const float* __restrict__ y2,
    const float* __restrict__ op1, const float* __restrict__ op2, float* __restrict__ xmid){
  __shared__ float wl[48*96];
  __shared__ float ylds[64][97];
  int b = blockIdx.x >> 6, h = blockIdx.x & 63;
  int tid = threadIdx.x;
  float acc[3][4];
  #pragma unroll
  for (int a = 0; a < 3; a++) { acc[a][0]=0; acc[a][1]=0; acc[a][2]=0; acc[a][3]=0; }
  for (int pass = 0; pass < 2; pass++){
    __syncthreads();
    const float* op = pass ? op2 : op1;
    const float* y  = pass ? y2  : y1;
    for (int i = tid; i < 48*96; i += 256) wl[i] = op[i];
    if (pass == 0){
      for (int i = tid; i < 64*96; i += 256){
        int wp = i / 96, d = i % 96;
        int wsp = (h & 1) ? 63 - wp : wp;
        ylds[wsp][d] = y[((size_t)b*4096 + h*64 + wp)*96 + d];
      }
    } else {
      for (int i = tid; i < 64*96; i += 256){
        int w = i / 96, d = i % 96;
        int t = w*64 + ((w & 1) ? 63 - h : h);
        ylds[w][d] = y[((size_t)b*4096 + t)*96 + d];
      }
    }
    __syncthreads();
    for (int it = 0; it < 3; it++){
      int i = tid + it*256;
      int w = i & 63, cb = i >> 6;
      #pragma unroll 4
      for (int d = 0; d < 96; d++){
        float yv = ylds[w][d];
        #pragma unroll
        for (int q = 0; q < 4; q++) acc[it][q] += yv * wl[(cb*4+q)*96 + d];
      }
    }
  }
  for (int it = 0; it < 3; it++){
    int i = tid + it*256;
    int w = i & 63, cb = i >> 6;
    #pragma unroll
    for (int q = 0; q < 4; q++){
      int c = cb*4 + q;
      size_t idx = (((size_t)b*48 + c)*64 + h)*64 + w;
      xmid[idx] = x[idx] + acc[it][q];
    }
  }
}

// ---------------- K7: LN(n2) + 1x1 conv f_pin (48->192) -> xp (B,192,H,W)
__global__ __launch_bounds__(256) void k7_ln_pin(const float* __restrict__ xmid,
    const float* __restrict__ nw, const float* __restrict__ nb,
    const float* __restrict__ pin, float* __restrict__ xp){
  __shared__ float wl[192*48];
  __shared__ float xl[48*65];
  __shared__ float mu_s[64], rs_s[64];
  int b = blockIdx.x >> 6, h = blockIdx.x & 63;
  int tid = threadIdx.x;
  for (int i = tid; i < 192*48; i += 256) wl[i] = pin[i];
  for (int i = tid; i < 48*64; i += 256){
    int c = i >> 6, w = i & 63;
    xl[c*65 + w] = xmid[(((size_t)b*48+c)*64 + h)*64 + w];
  }
  __syncthreads();
  {
    int r = tid >> 2, k = tid & 3;
    float s1 = 0.f, s2 = 0.f;
    #pragma unroll
    for (int cc = 0; cc < 12; cc++){
      float v = xl[(k*12+cc)*65 + r];
      s1 += v; s2 += v*v;
    }
    s1 += __shfl_xor(s1,1); s2 += __shfl_xor(s2,1);
    s1 += __shfl_xor(s1,2); s2 += __shfl_xor(s2,2);
    if (k == 0){
      float m = s1*(1.f/48.f);
      mu_s[r] = m;
      rs_s[r] = rsqrtf(s2*(1.f/48.f) - m*m + 1e-5f);
    }
  }
  __syncthreads();
  for (int i = tid; i < 48*64; i += 256){
    int c = i >> 6, w = i & 63;
    xl[c*65 + w] = (xl[c*65 + w] - mu_s[w])*rs_s[w]*nw[c] + nb[c];
  }
  __syncthreads();
  for (int i = tid; i < 48*64; i += 256){
    int w = i & 63, ob = i >> 6; int o0 = ob*4;
    float a0=0,a1=0,a2=0,a3=0;
    #pragma unroll 4
    for (int c = 0; c < 48; c++){
      float xv = xl[c*65 + w];
      a0 += xv*wl[(o0+0)*48+c];
      a1 += xv*wl[(o0+1)*48+c];
      a2 += xv*wl[(o0+2)*48+c];
      a3 += xv*wl[(o0+3)*48+c];
    }
    xp[(((size_t)b*192 + o0+0)*64 + h)*64 + w] = a0;
    xp[(((size_t)b*192 + o0+1)*64 + h)*64 + w] = a1;
    xp[(((size_t)b*192 + o0+2)*64 + h)*64 + w] = a2;
    xp[(((size_t)b*192 + o0+3)*64 + h)*64 + w] = a3;
  }
}

// ---------------- K9: direct 3x3 conv 48->48 on 32x32; optional fused 2x2-avg-pool input
__global__ __launch_bounds__(256) void k9_conv3(const float* __restrict__ in,
    const float* __restrict__ wgt, const float* __restrict__ bias, float* __restrict__ out,
    int pooled){
  __shared__ float sin_[48][3][34];
  __shared__ float wl[24*48*9];
  int bid = blockIdx.x;
  int coh = bid & 1, i0 = (bid >> 1) & 31, b = bid >> 6;
  int tid = threadIdx.x;
  for (int i = tid; i < 24*48*9; i += 256) wl[i] = wgt[coh*24*48*9 + i];
  for (int i = tid; i < 48*3*34; i += 256){
    int jx = i % 34, ky = (i/34) % 3, ci = i/(34*3);
    int r = i0 + ky - 1, j = jx - 1;
    float v = 0.f;
    if (r >= 0 && r < 32 && j >= 0 && j < 32){
      if (pooled){
        const float* xb = in + (((size_t)b*48 + ci)*64 + 2*r)*64 + 2*j;
        v = 0.25f*(xb[0] + xb[1] + xb[64] + xb[65]);
      } else {
        v = in[(((size_t)b*48 + ci)*32 + r)*32 + j];
      }
    }
    sin_[ci][ky][jx] = v;
  }
  __syncthreads();
  for (int i = tid; i < 24*32; i += 256){
    int j = i & 31, col = i >> 5;
    float acc = bias[coh*24 + col];
    for (int ci = 0; ci < 48; ci++){
      const float* wp = wl + ((size_t)col*48 + ci)*9;
      #pragma unroll
      for (int ky = 0; ky < 3; ky++)
        #pragma unroll
        for (int kx = 0; kx < 3; kx++)
          acc += sin_[ci][ky][j+kx] * wp[ky*3+kx];
    }
    out[(((size_t)b*48 + coh*24 + col)*32 + i0)*32 + j] = acc;
  }
}

// ---------------- K10: LN over C + relu on (B,48,32,32) — LDS-parallel, 32 blocks
__global__ __launch_bounds__(256) void k10_lnrelu(const float* __restrict__ in,
    const float* __restrict__ w, const float* __restrict__ bia, float* __restrict__ out){
  __shared__ float sl[48*65];
  __shared__ float mu_s[64], rs_s[64];
  int b = blockIdx.x >> 4, pblk = blockIdx.x & 15;
  int p0 = pblk*64;
  int tid = threadIdx.x;
  for (int i = tid; i < 48*64; i += 256){
    int c = i >> 6, pp = i & 63;
    sl[c*65 + pp] = in[((size_t)b*48 + c)*1024 + p0 + pp];
  }
  __syncthreads();
  {
    int r = tid >> 2, k = tid & 3;
    float s1 = 0.f, s2 = 0.f;
    #pragma unroll
    for (int cc = 0; cc < 12; cc++){
      float v = sl[(k*12+cc)*65 + r];
      s1 += v; s2 += v*v;
    }
    s1 += __shfl_xor(s1,1); s2 += __shfl_xor(s2,1);
    s1 += __shfl_xor(s1,2); s2 += __shfl_xor(s2,2);
    if (k == 0){
      float m = s1*(1.f/48.f);
      mu_s[r] = m;
      rs_s[r] = rsqrtf(s2*(1.f/48.f) - m*m + 1e-5f);
    }
  }
  __syncthreads();
  for (int i = tid; i < 48*64; i += 256){
    int c = i >> 6, pp = i & 63;
    float v = (sl[c*65 + pp] - mu_s[pp])*rs_s[pp]*w[c] + bia[c];
    out[((size_t)b*48 + c)*1024 + p0 + pp] = fmaxf(v, 0.f);
  }
}

// ---------------- K13: depthwise 3x3, pad 1, CH channels, 64x64
__global__ __launch_bounds__(256) void k13_dw(const float* __restrict__ in,
    const float* __restrict__ wgt, float* __restrict__ out, int CH){
  int idx = blockIdx.x*256 + threadIdx.x;
  if (idx >= 2*CH*4096) return;
  int w = idx & 63, h = (idx >> 6) & 63, c = (idx >> 12) % CH, b = idx / (CH*4096);
  const float* ip = in + ((size_t)b*CH + c)*4096;
  const float* wp = wgt + c*9;
  float acc = 0.f;
  #pragma unroll
  for (int ky = 0; ky < 3; ky++){
    int hh = h + ky - 1;
    if (hh < 0 || hh > 63) continue;
    #pragma unroll
    for (int kx = 0; kx < 3; kx++){
      int ww = w + kx - 1;
      if (ww < 0 || ww > 63) continue;
      acc += wp[ky*3+kx] * ip[hh*64 + ww];
    }
  }
  out[idx] = acc;
}

// ---------------- K14: 1x1 conv f_fus over concat(xd[:96], upsample(yb)) -> x1 (96 ch)
__global__ __launch_bounds__(256) void k14_fus(const float* __restrict__ xd,
    const float* __restrict__ yb, const float* __restrict__ fus, float* __restrict__ x1){
  __shared__ float wl[48*144];
  __shared__ float al[96][64];
  __shared__ float yl[48][32];
  int bid = blockIdx.x;
  int oh = bid & 1, h = (bid >> 1) & 63, b = bid >> 7;
  int tid = threadIdx.x;
  for (int i = tid; i < 48*144; i += 256) wl[i] = fus[(size_t)oh*48*144 + i];
  for (int i = tid; i < 96*64; i += 256){
    int ci = i >> 6, w = i & 63;
    al[ci][w] = xd[(((size_t)b*192 + ci)*64 + h)*64 + w];
  }
  for (int i = tid; i < 48*32; i += 256){
    int cj = i >> 5, j = i & 31;
    yl[cj][j] = yb[(((size_t)b*48 + cj)*32 + (h >> 1))*32 + j];
  }
  __syncthreads();
  for (int it = 0; it < 3; it++){
    int i = tid + it*256;
    int w = i & 63, ob = i >> 6; int o0 = ob*4;
    float a[4] = {0,0,0,0};
    #pragma unroll 4
    for (int ci = 0; ci < 96; ci++){
      float xv = al[ci][w];
      #pragma unroll
      for (int q = 0; q < 4; q++) a[q] += xv * wl[(o0+q)*144 + ci];
    }
    int w2 = w >> 1;
    #pragma unroll 4
    for (int cj = 0; cj < 48; cj++){
      float yv = yl[cj][w2];
      #pragma unroll
      for (int q = 0; q < 4; q++) a[q] += yv * wl[(o0+q)*144 + 96 + cj];
    }
    #pragma unroll
    for (int q = 0; q < 4; q++)
      x1[(((size_t)b*96 + oh*48 + o0 + q)*64 + h)*64 + w] = a[q];
  }
}

// ---------------- K16: gelu(x1d)*x2 -> 1x1 conv f_pout (96->48) -> + xmid -> out
__global__ __launch_bounds__(256) void k16_out(const float* __restrict__ x1d,
    const float* __restrict__ xd, const float* __restrict__ pout,
    const float* __restrict__ xmid, float* __restrict__ out){
  __shared__ float wl[48*96];
  __shared__ float gl[96][64];
  int b = blockIdx.x >> 6, h = blockIdx.x & 63;
  int tid = threadIdx.x;
  for (int i = tid; i < 48*96; i += 256) wl[i] = pout[i];
  for (int i = tid; i < 96*64; i += 256){
    int ch = i >> 6, w = i & 63;
    float a  = x1d[(((size_t)b*96 + ch)*64 + h)*64 + w];
    float x2 = xd[(((size_t)b*192 + 96 + ch)*64 + h)*64 + w];
    gl[ch][w] = geluf(a) * x2;
  }
  __syncthreads();
  for (int it = 0; it < 3; it++){
    int i = tid + it*256;
    int w = i & 63, cbk = i >> 6; int c0 = cbk*4;
    float a[4] = {0,0,0,0};
    #pragma unroll 4
    for (int ch = 0; ch < 96; ch++){
      float gv = gl[ch][w];
      #pragma unroll
      for (int q = 0; q < 4; q++) a[q] += gv * wl[(c0+q)*96 + ch];
    }
    #pragma unroll
    for (int q = 0; q < 4; q++){
      size_t idx = (((size_t)b*48 + c0 + q)*64 + h)*64 + w;
      out[idx] = xmid[idx] + a[q];
    }
  }
}

extern "C" void kernel_launch(void* const* d_in, const int* in_sizes, int n_in,
                              void* d_out, int out_size, void* d_ws, size_t ws_size,
                              hipStream_t stream){
  (void)in_sizes; (void)n_in; (void)out_size; (void)ws_size;
  const float* x    = (const float*)d_in[0];
  const float* n1w  = (const float*)d_in[1];
  const float* n1b  = (const float*)d_in[2];
  const float* n2w  = (const float*)d_in[3];
  const float* n2b  = (const float*)d_in[4];
  const float* mlnw[2] = {(const float*)d_in[5], (const float*)d_in[7]};
  const float* mlnb[2] = {(const float*)d_in[6], (const float*)d_in[8]};
  const float* fln1w = (const float*)d_in[9];
  const float* fln1b = (const float*)d_in[10];
  const float* fln2w = (const float*)d_in[11];
  const float* fln2b = (const float*)d_in[12];
  const float* inproj[2]  = {(const float*)d_in[13], (const float*)d_in[22]};
  const float* convw[2]   = {(const float*)d_in[14], (const float*)d_in[23]};
  const float* convb[2]   = {(const float*)d_in[15], (const float*)d_in[24]};
  const float* xproj[2]   = {(const float*)d_in[16], (const float*)d_in[25]};
  const float* dtw[2]     = {(const float*)d_in[17], (const float*)d_in[26]};
  const float* dtbp[2]    = {(const float*)d_in[18], (const float*)d_in[27]};
  const float* Alog[2]    = {(const float*)d_in[19], (const float*)d_in[28]};
  const float* Dp[2]      = {(const float*)d_in[20], (const float*)d_in[29]};
  const float* outproj[2] = {(const float*)d_in[21], (const float*)d_in[30]};
  const float* fpin  = (const float*)d_in[31];
  const float* fdw   = (const float*)d_in[32];
  const float* ffus  = (const float*)d_in[33];
  const float* fdwa  = (const float*)d_in[34];
  const float* fpout = (const float*)d_in[35];
  const float* fc1w  = (const float*)d_in[36];
  const float* fc1b  = (const float*)d_in[37];
  const float* fc2w  = (const float*)d_in[38];
  const float* fc2b  = (const float*)d_in[39];

  // workspace (floats), total 7,995,392 (= 32.0 MB, same as prior rounds)
  float* ws = (float*)d_ws;
  float* xmg = ws + 0;         // (4,4096,96)  -> later yall
  float* Vgb = ws + 1572864;   // (4,4096,48)  -> later x1db
  float* xcg = ws + 2359296;   // (4,4096,96)  -> later xpb (B,192,64,64)
  float* dtg = ws + 3932160;   // (4,4096,96)  -> later xdb
  float* Bmg = ws + 5505024;   // (4,4096,16)
  float* Cmg = ws + 5767168;   // (4,4096,16)
  float* Pb  = ws + 6029312;   // (512,1536)   -> Hin in-place, later x1b
  float* Sb  = ws + 6815744;   // (512,1536)   -> later pool bufs
  float* xmid= ws + 7602176;   // (B,48,64,64)
  float* yall = xmg;
  float* Hin  = Pb;
  float* ta   = Sb;
  float* tbuf = Sb + 98304;
  float* ybb  = Sb + 196608;
  float* xpb  = xcg;
  float* xdb  = dtg;
  float* x1b  = Pb;
  float* x1db = Vgb;

  kA_front<<<512,256,0,stream>>>(x, n1w, n1b,
      mlnw[0], mlnb[0], mlnw[1], mlnb[1], inproj[0], inproj[1], xmg, Vgb);
  kB_convscan<<<512,384,0,stream>>>(xmg,
      convw[0], convw[1], convb[0], convb[1], xproj[0], xproj[1],
      dtw[0], dtw[1], dtbp[0], dtbp[1], Alog[0], Alog[1],
      xcg, dtg, Bmg, Cmg, Pb, Sb);
  k4_comb  <<<24,256,0,stream>>>(Pb, Sb);
  k5_scan2 <<<512,384,0,stream>>>(dtg, xcg, Bmg, Cmg, Alog[0], Alog[1],
      Dp[0], Dp[1], inproj[0], inproj[1], Vgb, Hin, yall);
  k6_outproj<<<128,256,0,stream>>>(x, yall, yall + 786432, outproj[0], outproj[1], xmid);
  k7_ln_pin <<<128,256,0,stream>>>(xmid, n2w, n2b, fpin, xpb);
  k9_conv3  <<<128,256,0,stream>>>(x, fc1w, fc1b, ta, 1);
  k10_lnrelu<<<32,256,0,stream>>>(ta, fln1w, fln1b, tbuf);
  k9_conv3  <<<128,256,0,stream>>>(tbuf, fc2w, fc2b, ta, 0);
  k10_lnrelu<<<32,256,0,stream>>>(ta, fln2w, fln2b, ybb);
  k13_dw    <<<6144,256,0,stream>>>(xpb, fdw, xdb, 192);
  k14_fus   <<<256,256,0,stream>>>(xdb, ybb, ffus, x1b);
  k13_dw    <<<3072,256,0,stream>>>(x1b, fdwa, x1db, 96);
  k16_out   <<<128,256,0,stream>>>(x1db, xdb, fpout, xmid, (float*)d_out);
}

// Round 5
// 243.883 us; speedup vs baseline: 2.1557x; 1.0847x over previous
//
#include <hip/hip_runtime.h>

// SBSM block: B=2, C=48, H=W=64, L=4096, DI=96, DS=16, DCONV=4, DTR=3, HF=96
#define DEV __device__ __forceinline__

DEV float siluf(float x){ return x / (1.f + __expf(-x)); }
DEV float softplusf(float x){ return fmaxf(x, 0.f) + log1pf(expf(-fabsf(x))); }
DEV float geluf(float x){ return 0.5f * x * (1.f + erff(x * 0.70710678118654752440f)); }

// ---------------- kPE: positional-encoding table pe[4096][48] (recomputed every call)
__global__ __launch_bounds__(256) void kPE(float* __restrict__ pe){
  int i = blockIdx.x*256 + threadIdx.x;
  if (i >= 4096*48) return;
  int t = i / 48, c = i % 48;
  float ang = (float)t * __expf(-(float)(c & ~1) * (9.210340371976184f/48.f));
  pe[i] = (c & 1) ? cosf(ang) : sinf(ang);
}

// ---------------- kA: snake gather + LN(n1) + posenc + LN(mln) -> Vg(48) ; inproj xm-half -> xmg(96)
__global__ __launch_bounds__(256) void kA_front(const float* __restrict__ x,
    const float* __restrict__ n1w, const float* __restrict__ n1b,
    const float* __restrict__ mw0, const float* __restrict__ mb0,
    const float* __restrict__ mw1, const float* __restrict__ mb1,
    const float* __restrict__ ip0, const float* __restrict__ ip1,
    const float* __restrict__ peT,
    float* __restrict__ xmg, float* __restrict__ Vg){
  __shared__ alignas(16) float Vl[48*36];   // [c][r], pad 36
  __shared__ float Wt[48*97];               // transposed inproj xm-half: Wt[c][j]
  __shared__ float mu_s[32], rs_s[32];
  int bd = blockIdx.x >> 7, tile = blockIdx.x & 127;
  int dir = bd >> 1, b = bd & 1;
  int t0 = tile*32;
  int tid = threadIdx.x;
  const float* ip = dir ? ip1 : ip0;
  const float* mw = dir ? mw1 : mw0;
  const float* mb = dir ? mb1 : mb0;
  for (int i = tid; i < 96*48; i += 256){
    int j = i / 48, c = i % 48;
    Wt[c*97 + j] = ip[i];
  }
  for (int i = tid; i < 48*32; i += 256){
    int c = i >> 5, r = i & 31;
    int t = t0 + r;
    int h, w;
    if (dir == 0){ h = t >> 6; int wp = t & 63; w = (h & 1) ? 63 - wp : wp; }
    else         { w = t >> 6; int hp = t & 63; h = (w & 1) ? 63 - hp : hp; }
    Vl[c*36 + r] = x[(size_t)b*48*4096 + c*4096 + h*64 + w];
  }
  __syncthreads();
  // stats round 1
  {
    int r = tid >> 3, k = tid & 7;
    float s1 = 0.f, s2 = 0.f;
    #pragma unroll
    for (int cc = 0; cc < 6; cc++){
      float v = Vl[(k*6+cc)*36 + r];
      s1 += v; s2 += v*v;
    }
    s1 += __shfl_xor(s1,1); s2 += __shfl_xor(s2,1);
    s1 += __shfl_xor(s1,2); s2 += __shfl_xor(s2,2);
    s1 += __shfl_xor(s1,4); s2 += __shfl_xor(s2,4);
    if (k == 0){
      float m = s1*(1.f/48.f);
      mu_s[r] = m;
      rs_s[r] = rsqrtf(s2*(1.f/48.f) - m*m + 1e-5f);
    }
  }
  __syncthreads();
  // apply LN1 + posenc (table)
  for (int i = tid; i < 32*48; i += 256){
    int r = i / 48, c = i % 48;
    float v = Vl[c*36 + r];
    float xn = (v - mu_s[r])*rs_s[r]*n1w[c] + n1b[c];
    Vl[c*36 + r] = xn + peT[(size_t)(t0 + r)*48 + c];
  }
  __syncthreads();
  // stats round 2
  {
    int r = tid >> 3, k = tid & 7;
    float s1 = 0.f, s2 = 0.f;
    #pragma unroll
    for (int cc = 0; cc < 6; cc++){
      float v = Vl[(k*6+cc)*36 + r];
      s1 += v; s2 += v*v;
    }
    s1 += __shfl_xor(s1,1); s2 += __shfl_xor(s2,1);
    s1 += __shfl_xor(s1,2); s2 += __shfl_xor(s2,2);
    s1 += __shfl_xor(s1,4); s2 += __shfl_xor(s2,4);
    if (k == 0){
      float m = s1*(1.f/48.f);
      mu_s[r] = m;
      rs_s[r] = rsqrtf(s2*(1.f/48.f) - m*m + 1e-5f);
    }
  }
  __syncthreads();
  // apply LN2 (mln), write Vg coalesced
  for (int i = tid; i < 32*48; i += 256){
    int r = i / 48, c = i % 48;
    float v = Vl[c*36 + r];
    float v2 = (v - mu_s[r])*rs_s[r]*mw[c] + mb[c];
    Vl[c*36 + r] = v2;
    Vg[((size_t)bd*4096 + t0 + r)*48 + c] = v2;
  }
  __syncthreads();
  // xm GEMV: tasks (j 0..95, rb 0..7), 4 r per task via float4
  for (int k = 0; k < 3; k++){
    int i = tid + k*256;
    int j = i % 96, rb = i / 96;
    float a0=0.f, a1=0.f, a2=0.f, a3=0.f;
    #pragma unroll 4
    for (int c = 0; c < 48; c++){
      float wv = Wt[c*97 + j];
      const float4 v4 = *(const float4*)&Vl[c*36 + rb*4];
      a0 += wv*v4.x; a1 += wv*v4.y; a2 += wv*v4.z; a3 += wv*v4.w;
    }
    size_t g = ((size_t)bd*4096 + t0 + rb*4)*96 + j;
    xmg[g] = a0; xmg[g+96] = a1; xmg[g+192] = a2; xmg[g+288] = a3;
  }
}

// ---------------- kB: causal conv4+silu + xproj + dt/B/C + scan pass-1 (chunk=32)
// LDS ~51 KB -> 3 blocks/CU.
__global__ __launch_bounds__(384) void kB_convscan(const float* __restrict__ xmg,
    const float* __restrict__ cwp0, const float* __restrict__ cwp1,
    const float* __restrict__ cbp0, const float* __restrict__ cbp1,
    const float* __restrict__ xpp0, const float* __restrict__ xpp1,
    const float* __restrict__ dwp0, const float* __restrict__ dwp1,
    const float* __restrict__ dbp0, const float* __restrict__ dbp1,
    const float* __restrict__ Alog0, const float* __restrict__ Alog1,
    float* __restrict__ xcg, float* __restrict__ dtg,
    float* __restrict__ Bmg, float* __restrict__ Cmg,
    float* __restrict__ P, float* __restrict__ S){
  __shared__ union UB {
    float xml[96*36];                               // [d][tl] tl 0..34 (3 halo)
    struct { float xwl[35*96]; float xdbl[35*33]; } p;
  } ub;
  __shared__ float xcl[96*33];
  __shared__ float dtl[96*33];
  __shared__ alignas(16) float Bl[32*16], Cl[32*16];
  __shared__ float cw[96*4], cbv[96], dwl[96*3], dbl[96];
  int bd = blockIdx.x >> 7, tile = blockIdx.x & 127;
  int dir = bd >> 1;
  int t0 = tile*32;
  int tid = threadIdx.x;
  const float* cwp = dir ? cwp1 : cwp0;
  const float* cbp = dir ? cbp1 : cbp0;
  const float* xpp = dir ? xpp1 : xpp0;
  const float* dwp = dir ? dwp1 : dwp0;
  const float* dbp = dir ? dbp1 : dbp0;
  const float* Alog = dir ? Alog1 : Alog0;
  // phase 1: stage xm tile + halo, small weights
  for (int i = tid; i < 35*96; i += 384){
    int tl = i / 96, d = i % 96;
    int t = t0 - 3 + tl;
    ub.xml[d*36 + tl] = (t >= 0) ? xmg[((size_t)bd*4096 + t)*96 + d] : 0.f;
  }
  for (int i = tid; i < 96*4;  i += 384) cw[i] = cwp[i];
  for (int i = tid; i < 96*3;  i += 384) dwl[i] = dwp[i];
  for (int i = tid; i < 96;    i += 384){ cbv[i] = cbp[i]; dbl[i] = dbp[i]; }
  __syncthreads();
  // phase 2: conv4 + silu
  for (int i = tid; i < 96*32; i += 384){
    int d = i >> 5, t = i & 31;
    float acc = cbv[d];
    #pragma unroll
    for (int k = 0; k < 4; k++) acc += cw[d*4+k]*ub.xml[d*36 + t + k];
    xcl[d*33 + t] = siluf(acc);
  }
  __syncthreads();
  // phase 3: stage xproj weights (overwrites xml)
  for (int i = tid; i < 35*96; i += 384) ub.p.xwl[i] = xpp[i];
  __syncthreads();
  // phase 4: xproj (96 -> 35)
  for (int i = tid; i < 35*32; i += 384){
    int j = i / 32, t = i % 32;
    float acc = 0.f;
    #pragma unroll 4
    for (int d = 0; d < 96; d++) acc += xcl[d*33 + t]*ub.p.xwl[j*96 + d];
    ub.p.xdbl[j*33 + t] = acc;
  }
  __syncthreads();
  // phase 5: dt = softplus(...); B/C split
  for (int i = tid; i < 96*32; i += 384){
    int d = i >> 5, t = i & 31;
    float v = dbl[d];
    #pragma unroll
    for (int r = 0; r < 3; r++) v += ub.p.xdbl[r*33 + t]*dwl[d*3 + r];
    dtl[d*33 + t] = softplusf(v);
  }
  for (int i = tid; i < 32*16; i += 384){
    int t = i / 16, s = i % 16;
    Bl[t*16 + s] = ub.p.xdbl[(3+s)*33 + t];
    Cl[t*16 + s] = ub.p.xdbl[(19+s)*33 + t];
  }
  __syncthreads();
  // phase 6: global writes + scan pass 1
  for (int i = tid; i < 32*96; i += 384){
    int t = i / 96, d = i % 96;
    size_t g = ((size_t)bd*4096 + t0 + t)*96 + d;
    xcg[g] = xcl[d*33 + t];
    dtg[g] = dtl[d*33 + t];
  }
  for (int i = tid; i < 32*16; i += 384){
    int t = i / 16, s = i % 16;
    size_t g = ((size_t)bd*4096 + t0 + t)*16 + s;
    Bmg[g] = Bl[t*16 + s];
    Cmg[g] = Cl[t*16 + s];
  }
  {
    int d = tid >> 2, q = tid & 3;
    float A0 = -__expf(Alog[d*16 + q*4 + 0]);
    float A1 = -__expf(Alog[d*16 + q*4 + 1]);
    float A2 = -__expf(Alog[d*16 + q*4 + 2]);
    float A3 = -__expf(Alog[d*16 + q*4 + 3]);
    float h0=0.f,h1=0.f,h2=0.f,h3=0.f, p0=1.f,p1=1.f,p2=1.f,p3=1.f;
    #pragma unroll 4
    for (int t = 0; t < 32; t++){
      float dtd = dtl[d*33 + t];
      float u = dtd * xcl[d*33 + t];
      const float4 b4 = *(const float4*)&Bl[t*16 + q*4];
      float a0 = __expf(dtd*A0), a1 = __expf(dtd*A1), a2 = __expf(dtd*A2), a3 = __expf(dtd*A3);
      h0 = a0*h0 + u*b4.x; p0 *= a0;
      h1 = a1*h1 + u*b4.y; p1 *= a1;
      h2 = a2*h2 + u*b4.z; p2 *= a2;
      h3 = a3*h3 + u*b4.w; p3 *= a3;
    }
    size_t ob = (size_t)blockIdx.x*1536 + d*16 + q*4;
    *(float4*)&P[ob] = make_float4(p0,p1,p2,p3);
    *(float4*)&S[ob] = make_float4(h0,h1,h2,h3);
  }
}

// ---------------- k4: sequential chunk combine over 128 chunks, IN PLACE (Hin = P).
__global__ __launch_bounds__(256) void k4_comb(float* __restrict__ P, const float* __restrict__ S){
  int tid2 = blockIdx.x*256 + threadIdx.x;   // 6144 lanes
  int bd = tid2 / 1536, r = tid2 % 1536;
  size_t idx = (size_t)bd*128*1536 + r;
  const int ST = 1536;
  float pb0,pb1,pb2,pb3,pb4,pb5,pb6,pb7, sb0,sb1,sb2,sb3,sb4,sb5,sb6,sb7;
  pb0=P[idx+0*ST]; sb0=S[idx+0*ST]; pb1=P[idx+1*ST]; sb1=S[idx+1*ST];
  pb2=P[idx+2*ST]; sb2=S[idx+2*ST]; pb3=P[idx+3*ST]; sb3=S[idx+3*ST];
  pb4=P[idx+4*ST]; sb4=S[idx+4*ST]; pb5=P[idx+5*ST]; sb5=S[idx+5*ST];
  pb6=P[idx+6*ST]; sb6=S[idx+6*ST]; pb7=P[idx+7*ST]; sb7=S[idx+7*ST];
  float h = 0.f;
  for (int c0 = 0; c0 < 128; c0 += 8){
    float pn0=0,sn0=0,pn1=0,sn1=0,pn2=0,sn2=0,pn3=0,sn3=0;
    float pn4=0,sn4=0,pn5=0,sn5=0,pn6=0,sn6=0,pn7=0,sn7=0;
    if (c0 + 8 < 128){
      pn0=P[idx+(size_t)(c0+8)*ST];  sn0=S[idx+(size_t)(c0+8)*ST];
      pn1=P[idx+(size_t)(c0+9)*ST];  sn1=S[idx+(size_t)(c0+9)*ST];
      pn2=P[idx+(size_t)(c0+10)*ST]; sn2=S[idx+(size_t)(c0+10)*ST];
      pn3=P[idx+(size_t)(c0+11)*ST]; sn3=S[idx+(size_t)(c0+11)*ST];
      pn4=P[idx+(size_t)(c0+12)*ST]; sn4=S[idx+(size_t)(c0+12)*ST];
      pn5=P[idx+(size_t)(c0+13)*ST]; sn5=S[idx+(size_t)(c0+13)*ST];
      pn6=P[idx+(size_t)(c0+14)*ST]; sn6=S[idx+(size_t)(c0+14)*ST];
      pn7=P[idx+(size_t)(c0+15)*ST]; sn7=S[idx+(size_t)(c0+15)*ST];
    }
    P[idx+(size_t)(c0+0)*ST] = h; h = pb0*h + sb0;
    P[idx+(size_t)(c0+1)*ST] = h; h = pb1*h + sb1;
    P[idx+(size_t)(c0+2)*ST] = h; h = pb2*h + sb2;
    P[idx+(size_t)(c0+3)*ST] = h; h = pb3*h + sb3;
    P[idx+(size_t)(c0+4)*ST] = h; h = pb4*h + sb4;
    P[idx+(size_t)(c0+5)*ST] = h; h = pb5*h + sb5;
    P[idx+(size_t)(c0+6)*ST] = h; h = pb6*h + sb6;
    P[idx+(size_t)(c0+7)*ST] = h; h = pb7*h + sb7;
    pb0=pn0;sb0=sn0;pb1=pn1;sb1=sn1;pb2=pn2;sb2=sn2;pb3=pn3;sb3=sn3;
    pb4=pn4;sb4=sn4;pb5=pn5;sb5=sn5;pb6=pn6;sb6=sn6;pb7=pn7;sb7=sn7;
  }
}

// ---------------- k5: pass-3 rescan (+D term) -> yl ; then z GEMV + gate, LDS phase-union.
// LDS = 40,960 B exactly -> 3-4 blocks/CU.
__global__ __launch_bounds__(384) void k5_scan2(const float* __restrict__ dtg,
    const float* __restrict__ xcg, const float* __restrict__ Bmg, const float* __restrict__ Cmg,
    const float* __restrict__ Alog0, const float* __restrict__ Alog1,
    const float* __restrict__ Dp0, const float* __restrict__ Dp1,
    const float* __restrict__ ip0, const float* __restrict__ ip1,
    const float* __restrict__ Vg, const float* __restrict__ Hin, float* __restrict__ yout){
  __shared__ union U5 {
    struct { float dts[32*96]; float xcs[32*96]; } s;   // scan phase
    struct { float Wzt[48*96]; float Vgs[32*48]; } e;   // epilogue phase
  } u;
  __shared__ alignas(16) float Bl[32*16], Cl[32*16];
  __shared__ float yl[32*96];
  int task = blockIdx.x;
  int bd = task >> 7, ch = task & 127;
  int t0 = ch*32;
  int tid = threadIdx.x;
  const float* ip   = (bd >= 2) ? ip1 : ip0;
  const float* Alog = (bd >= 2) ? Alog1 : Alog0;
  const float* Dp   = (bd >= 2) ? Dp1 : Dp0;
  for (int i = tid; i < 32*96; i += 384){
    int t = i / 96, dd = i % 96;
    size_t g = ((size_t)bd*4096 + t0 + t)*96 + dd;
    u.s.dts[i] = dtg[g];
    u.s.xcs[i] = xcg[g];
  }
  for (int i = tid; i < 32*16; i += 384){
    size_t g = ((size_t)bd*4096 + t0)*16 + i;
    Bl[i] = Bmg[g];
    Cl[i] = Cmg[g];
  }
  __syncthreads();
  // rescan, 2x unrolled, D-term folded into yl
  {
    int d = tid >> 2, q = tid & 3;
    float A0 = -__expf(Alog[d*16 + q*4 + 0]);
    float A1 = -__expf(Alog[d*16 + q*4 + 1]);
    float A2 = -__expf(Alog[d*16 + q*4 + 2]);
    float A3 = -__expf(Alog[d*16 + q*4 + 3]);
    float Dd = Dp[d];
    const float4 h4 = *(const float4*)&Hin[(size_t)task*1536 + d*16 + q*4];
    float h0 = h4.x, h1 = h4.y, h2 = h4.z, h3 = h4.w;
    for (int t = 0; t < 32; t += 2){
      float dtdA = u.s.dts[t*96 + d];
      float xcvA = u.s.xcs[t*96 + d];
      float dtdB = u.s.dts[(t+1)*96 + d];
      float xcvB = u.s.xcs[(t+1)*96 + d];
      float uA = dtdA * xcvA, uB = dtdB * xcvB;
      const float4 b4A = *(const float4*)&Bl[t*16 + q*4];
      const float4 c4A = *(const float4*)&Cl[t*16 + q*4];
      const float4 b4B = *(const float4*)&Bl[(t+1)*16 + q*4];
      const float4 c4B = *(const float4*)&Cl[(t+1)*16 + q*4];
      float a0 = __expf(dtdA*A0), a1 = __expf(dtdA*A1), a2 = __expf(dtdA*A2), a3 = __expf(dtdA*A3);
      float e0 = __expf(dtdB*A0), e1 = __expf(dtdB*A1), e2 = __expf(dtdB*A2), e3 = __expf(dtdB*A3);
      h0 = a0*h0 + uA*b4A.x;
      h1 = a1*h1 + uA*b4A.y;
      h2 = a2*h2 + uA*b4A.z;
      h3 = a3*h3 + uA*b4A.w;
      float pyA = (h0*c4A.x + h1*c4A.y) + (h2*c4A.z + h3*c4A.w);
      h0 = e0*h0 + uB*b4B.x;
      h1 = e1*h1 + uB*b4B.y;
      h2 = e2*h2 + uB*b4B.z;
      h3 = e3*h3 + uB*b4B.w;
      float pyB = (h0*c4B.x + h1*c4B.y) + (h2*c4B.z + h3*c4B.w);
      pyA += __shfl_xor(pyA, 1);  pyB += __shfl_xor(pyB, 1);
      pyA += __shfl_xor(pyA, 2);  pyB += __shfl_xor(pyB, 2);
      if (q == 0){
        yl[t*96 + d]     = pyA + xcvA*Dd;
        yl[(t+1)*96 + d] = pyB + xcvB*Dd;
      }
    }
  }
  __syncthreads();
  // stage epilogue data into the (now dead) scan buffers
  for (int i = tid; i < 96*48; i += 384){
    int j = i % 96, c = i / 96;
    u.e.Wzt[c*96 + j] = ip[(96 + j)*48 + c];
  }
  for (int i = tid; i < 32*48; i += 384){
    int t = i / 48, c = i % 48;
    u.e.Vgs[i] = Vg[((size_t)bd*4096 + t0 + t)*48 + c];
  }
  __syncthreads();
  // z GEMV (48 -> 96) + silu gate
  for (int i = tid; i < 32*96; i += 384){
    int t = i / 96, dd = i % 96;
    float z = 0.f;
    #pragma unroll 4
    for (int c = 0; c < 48; c++) z += u.e.Wzt[c*96 + dd] * u.e.Vgs[t*48 + c];
    size_t g = ((size_t)bd*4096 + t0 + t)*96 + dd;
    yout[g] = yl[i] * siluf(z);
  }
}

// ---------------- K6: un-snake + outproj (96->48) both dirs + residual -> xmid
__global__ __launch_bounds__(256) void k6_outproj(const float* __restrict__ x,
    const float* __restrict__ y1, const float* __restrict__ y2,
    const float* __restrict__ op1, const float* __restrict__ op2, float* __restrict__ xmid){
  __shared__ float wl[48*96];
  __shared__ float ylds[64][97];
  int b = blockIdx.x >> 6, h = blockIdx.x & 63;
  int tid = threadIdx.x;
  float acc[3][4];
  #pragma unroll
  for (int a = 0; a < 3; a++) { acc[a][0]=0; acc[a][1]=0; acc[a][2]=0; acc[a][3]=0; }
  for (int pass = 0; pass < 2; pass++){
    __syncthreads();
    const float* op = pass ? op2 : op1;
    const float* y  = pass ? y2  : y1;
    for (int i = tid; i < 48*96; i += 256) wl[i] = op[i];
    if (pass == 0){
      for (int i = tid; i < 64*96; i += 256){
        int wp = i / 96, d = i % 96;
        int wsp = (h & 1) ? 63 - wp : wp;
        ylds[wsp][d] = y[((size_t)b*4096 + h*64 + wp)*96 + d];
      }
    } else {
      for (int i = tid; i < 64*96; i += 256){
        int w = i / 96, d = i % 96;
        int t = w*64 + ((w & 1) ? 63 - h : h);
        ylds[w][d] = y[((size_t)b*4096 + t)*96 + d];
      }
    }
    __syncthreads();
    for (int it = 0; it < 3; it++){
      int i = tid + it*256;
      int w = i & 63, cb = i >> 6;
      #pragma unroll 4
      for (int d = 0; d < 96; d++){
        float yv = ylds[w][d];
        #pragma unroll
        for (int q = 0; q < 4; q++) acc[it][q] += yv * wl[(cb*4+q)*96 + d];
      }
    }
  }
  for (int it = 0; it < 3; it++){
    int i = tid + it*256;
    int w = i & 63, cb = i >> 6;
    #pragma unroll
    for (int q = 0; q < 4; q++){
      int c = cb*4 + q;
      size_t idx = (((size_t)b*48 + c)*64 + h)*64 + w;
      xmid[idx] = x[idx] + acc[it][q];
    }
  }
}

// ---------------- K7: LN(n2) + 1x1 conv f_pin (48->192) -> xp (B,192,H,W)
__global__ __launch_bounds__(256) void k7_ln_pin(const float* __restrict__ xmid,
    const float* __restrict__ nw, const float* __restrict__ nb,
    const float* __restrict__ pin, float* __restrict__ xp){
  __shared__ float wl[192*48];
  __shared__ float xl[48*65];
  __shared__ float mu_s[64], rs_s[64];
  int b = blockIdx.x >> 6, h = blockIdx.x & 63;
  int tid = threadIdx.x;
  for (int i = tid; i < 192*48; i += 256) wl[i] = pin[i];
  for (int i = tid; i < 48*64; i += 256){
    int c = i >> 6, w = i & 63;
    xl[c*65 + w] = xmid[(((size_t)b*48+c)*64 + h)*64 + w];
  }
  __syncthreads();
  {
    int r = tid >> 2, k = tid & 3;
    float s1 = 0.f, s2 = 0.f;
    #pragma unroll
    for (int cc = 0; cc < 12; cc++){
      float v = xl[(k*12+cc)*65 + r];
      s1 += v; s2 += v*v;
    }
    s1 += __shfl_xor(s1,1); s2 += __shfl_xor(s2,1);
    s1 += __shfl_xor(s1,2); s2 += __shfl_xor(s2,2);
    if (k == 0){
      float m = s1*(1.f/48.f);
      mu_s[r] = m;
      rs_s[r] = rsqrtf(s2*(1.f/48.f) - m*m + 1e-5f);
    }
  }
  __syncthreads();
  for (int i = tid; i < 48*64; i += 256){
    int c = i >> 6, w = i & 63;
    xl[c*65 + w] = (xl[c*65 + w] - mu_s[w])*rs_s[w]*nw[c] + nb[c];
  }
  __syncthreads();
  for (int i = tid; i < 48*64; i += 256){
    int w = i & 63, ob = i >> 6; int o0 = ob*4;
    float a0=0,a1=0,a2=0,a3=0;
    #pragma unroll 4
    for (int c = 0; c < 48; c++){
      float xv = xl[c*65 + w];
      a0 += xv*wl[(o0+0)*48+c];
      a1 += xv*wl[(o0+1)*48+c];
      a2 += xv*wl[(o0+2)*48+c];
      a3 += xv*wl[(o0+3)*48+c];
    }
    xp[(((size_t)b*192 + o0+0)*64 + h)*64 + w] = a0;
    xp[(((size_t)b*192 + o0+1)*64 + h)*64 + w] = a1;
    xp[(((size_t)b*192 + o0+2)*64 + h)*64 + w] = a2;
    xp[(((size_t)b*192 + o0+3)*64 + h)*64 + w] = a3;
  }
}

// ---------------- K9: direct 3x3 conv 48->48 on 32x32; optional fused 2x2-avg-pool input
__global__ __launch_bounds__(256) void k9_conv3(const float* __restrict__ in,
    const float* __restrict__ wgt, const float* __restrict__ bias, float* __restrict__ out,
    int pooled){
  __shared__ float sin_[48][3][34];
  __shared__ float wl[24*48*9];
  int bid = blockIdx.x;
  int coh = bid & 1, i0 = (bid >> 1) & 31, b = bid >> 6;
  int tid = threadIdx.x;
  for (int i = tid; i < 24*48*9; i += 256) wl[i] = wgt[coh*24*48*9 + i];
  for (int i = tid; i < 48*3*34; i += 256){
    int jx = i % 34, ky = (i/34) % 3, ci = i/(34*3);
    int r = i0 + ky - 1, j = jx - 1;
    float v = 0.f;
    if (r >= 0 && r < 32 && j >= 0 && j < 32){
      if (pooled){
        const float* xb = in + (((size_t)b*48 + ci)*64 + 2*r)*64 + 2*j;
        v = 0.25f*(xb[0] + xb[1] + xb[64] + xb[65]);
      } else {
        v = in[(((size_t)b*48 + ci)*32 + r)*32 + j];
      }
    }
    sin_[ci][ky][jx] = v;
  }
  __syncthreads();
  for (int i = tid; i < 24*32; i += 256){
    int j = i & 31, col = i >> 5;
    float acc = bias[coh*24 + col];
    for (int ci = 0; ci < 48; ci++){
      const float* wp = wl + ((size_t)col*48 + ci)*9;
      #pragma unroll
      for (int ky = 0; ky < 3; ky++)
        #pragma unroll
        for (int kx = 0; kx < 3; kx++)
          acc += sin_[ci][ky][j+kx] * wp[ky*3+kx];
    }
    out[(((size_t)b*48 + coh*24 + col)*32 + i0)*32 + j] = acc;
  }
}

// ---------------- K10: LN over C + relu on (B,48,32,32) — LDS-parallel, 32 blocks
__global__ __launch_bounds__(256) void k10_lnrelu(const float* __restrict__ in,
    const float* __restrict__ w, const float* __restrict__ bia, float* __restrict__ out){
  __shared__ float sl[48*65];
  __shared__ float mu_s[64], rs_s[64];
  int b = blockIdx.x >> 4, pblk = blockIdx.x & 15;
  int p0 = pblk*64;
  int tid = threadIdx.x;
  for (int i = tid; i < 48*64; i += 256){
    int c = i >> 6, pp = i & 63;
    sl[c*65 + pp] = in[((size_t)b*48 + c)*1024 + p0 + pp];
  }
  __syncthreads();
  {
    int r = tid >> 2, k = tid & 3;
    float s1 = 0.f, s2 = 0.f;
    #pragma unroll
    for (int cc = 0; cc < 12; cc++){
      float v = sl[(k*12+cc)*65 + r];
      s1 += v; s2 += v*v;
    }
    s1 += __shfl_xor(s1,1); s2 += __shfl_xor(s2,1);
    s1 += __shfl_xor(s1,2); s2 += __shfl_xor(s2,2);
    if (k == 0){
      float m = s1*(1.f/48.f);
      mu_s[r] = m;
      rs_s[r] = rsqrtf(s2*(1.f/48.f) - m*m + 1e-5f);
    }
  }
  __syncthreads();
  for (int i = tid; i < 48*64; i += 256){
    int c = i >> 6, pp = i & 63;
    float v = (sl[c*65 + pp] - mu_s[pp])*rs_s[pp]*w[c] + bia[c];
    out[((size_t)b*48 + c)*1024 + p0 + pp] = fmaxf(v, 0.f);
  }
}

// ---------------- K13: depthwise 3x3, pad 1, CH channels, 64x64
__global__ __launch_bounds__(256) void k13_dw(const float* __restrict__ in,
    const float* __restrict__ wgt, float* __restrict__ out, int CH){
  int idx = blockIdx.x*256 + threadIdx.x;
  if (idx >= 2*CH*4096) return;
  int w = idx & 63, h = (idx >> 6) & 63, c = (idx >> 12) % CH, b = idx / (CH*4096);
  const float* ip = in + ((size_t)b*CH + c)*4096;
  const float* wp = wgt + c*9;
  float acc = 0.f;
  #pragma unroll
  for (int ky = 0; ky < 3; ky++){
    int hh = h + ky - 1;
    if (hh < 0 || hh > 63) continue;
    #pragma unroll
    for (int kx = 0; kx < 3; kx++){
      int ww = w + kx - 1;
      if (ww < 0 || ww > 63) continue;
      acc += wp[ky*3+kx] * ip[hh*64 + ww];
    }
  }
  out[idx] = acc;
}

// ---------------- K14: 1x1 conv f_fus over concat(xd[:96], upsample(yb)) -> x1 (96 ch)
__global__ __launch_bounds__(256) void k14_fus(const float* __restrict__ xd,
    const float* __restrict__ yb, const float* __restrict__ fus, float* __restrict__ x1){
  __shared__ float wl[48*144];
  __shared__ float al[96][64];
  __shared__ float yl[48][32];
  int bid = blockIdx.x;
  int oh = bid & 1, h = (bid >> 1) & 63, b = bid >> 7;
  int tid = threadIdx.x;
  for (int i = tid; i < 48*144; i += 256) wl[i] = fus[(size_t)oh*48*144 + i];
  for (int i = tid; i < 96*64; i += 256){
    int ci = i >> 6, w = i & 63;
    al[ci][w] = xd[(((size_t)b*192 + ci)*64 + h)*64 + w];
  }
  for (int i = tid; i < 48*32; i += 256){
    int cj = i >> 5, j = i & 31;
    yl[cj][j] = yb[(((size_t)b*48 + cj)*32 + (h >> 1))*32 + j];
  }
  __syncthreads();
  for (int it = 0; it < 3; it++){
    int i = tid + it*256;
    int w = i & 63, ob = i >> 6; int o0 = ob*4;
    float a[4] = {0,0,0,0};
    #pragma unroll 4
    for (int ci = 0; ci < 96; ci++){
      float xv = al[ci][w];
      #pragma unroll
      for (int q = 0; q < 4; q++) a[q] += xv * wl[(o0+q)*144 + ci];
    }
    int w2 = w >> 1;
    #pragma unroll 4
    for (int cj = 0; cj < 48; cj++){
      float yv = yl[cj][w2];
      #pragma unroll
      for (int q = 0; q < 4; q++) a[q] += yv * wl[(o0+q)*144 + 96 + cj];
    }
    #pragma unroll
    for (int q = 0; q < 4; q++)
      x1[(((size_t)b*96 + oh*48 + o0 + q)*64 + h)*64 + w] = a[q];
  }
}

// ---------------- K16: gelu(x1d)*x2 -> 1x1 conv f_pout (96->48) -> + xmid -> out
__global__ __launch_bounds__(256) void k16_out(const float* __restrict__ x1d,
    const float* __restrict__ xd, const float* __restrict__ pout,
    const float* __restrict__ xmid, float* __restrict__ out){
  __shared__ float wl[48*96];
  __shared__ float gl[96][64];
  int b = blockIdx.x >> 6, h = blockIdx.x & 63;
  int tid = threadIdx.x;
  for (int i = tid; i < 48*96; i += 256) wl[i] = pout[i];
  for (int i = tid; i < 96*64; i += 256){
    int ch = i >> 6, w = i & 63;
    float a  = x1d[(((size_t)b*96 + ch)*64 + h)*64 + w];
    float x2 = xd[(((size_t)b*192 + 96 + ch)*64 + h)*64 + w];
    gl[ch][w] = geluf(a) * x2;
  }
  __syncthreads();
  for (int it = 0; it < 3; it++){
    int i = tid + it*256;
    int w = i & 63, cbk = i >> 6; int c0 = cbk*4;
    float a[4] = {0,0,0,0};
    #pragma unroll 4
    for (int ch = 0; ch < 96; ch++){
      float gv = gl[ch][w];
      #pragma unroll
      for (int q = 0; q < 4; q++) a[q] += gv * wl[(c0+q)*96 + ch];
    }
    #pragma unroll
    for (int q = 0; q < 4; q++){
      size_t idx = (((size_t)b*48 + c0 + q)*64 + h)*64 + w;
      out[idx] = xmid[idx] + a[q];
    }
  }
}

extern "C" void kernel_launch(void* const* d_in, const int* in_sizes, int n_in,
                              void* d_out, int out_size, void* d_ws, size_t ws_size,
                              hipStream_t stream){
  (void)in_sizes; (void)n_in; (void)out_size; (void)ws_size;
  const float* x    = (const float*)d_in[0];
  const float* n1w  = (const float*)d_in[1];
  const float* n1b  = (const float*)d_in[2];
  const float* n2w  = (const float*)d_in[3];
  const float* n2b  = (const float*)d_in[4];
  const float* mlnw[2] = {(const float*)d_in[5], (const float*)d_in[7]};
  const float* mlnb[2] = {(const float*)d_in[6], (const float*)d_in[8]};
  const float* fln1w = (const float*)d_in[9];
  const float* fln1b = (const float*)d_in[10];
  const float* fln2w = (const float*)d_in[11];
  const float* fln2b = (const float*)d_in[12];
  const float* inproj[2]  = {(const float*)d_in[13], (const float*)d_in[22]};
  const float* convw[2]   = {(const float*)d_in[14], (const float*)d_in[23]};
  const float* convb[2]   = {(const float*)d_in[15], (const float*)d_in[24]};
  const float* xproj[2]   = {(const float*)d_in[16], (const float*)d_in[25]};
  const float* dtw[2]     = {(const float*)d_in[17], (const float*)d_in[26]};
  const float* dtbp[2]    = {(const float*)d_in[18], (const float*)d_in[27]};
  const float* Alog[2]    = {(const float*)d_in[19], (const float*)d_in[28]};
  const float* Dp[2]      = {(const float*)d_in[20], (const float*)d_in[29]};
  const float* outproj[2] = {(const float*)d_in[21], (const float*)d_in[30]};
  const float* fpin  = (const float*)d_in[31];
  const float* fdw   = (const float*)d_in[32];
  const float* ffus  = (const float*)d_in[33];
  const float* fdwa  = (const float*)d_in[34];
  const float* fpout = (const float*)d_in[35];
  const float* fc1w  = (const float*)d_in[36];
  const float* fc1b  = (const float*)d_in[37];
  const float* fc2w  = (const float*)d_in[38];
  const float* fc2b  = (const float*)d_in[39];

  // workspace (floats), total 7,995,392 (= 32.0 MB, same as prior rounds)
  float* ws = (float*)d_ws;
  float* xmg = ws + 0;         // (4,4096,96)  -> later yall
  float* Vgb = ws + 1572864;   // (4,4096,48)  -> later x1db
  float* xcg = ws + 2359296;   // (4,4096,96)  -> later xpb (B,192,64,64)
  float* dtg = ws + 3932160;   // (4,4096,96)  -> later xdb
  float* Bmg = ws + 5505024;   // (4,4096,16)
  float* Cmg = ws + 5767168;   // (4,4096,16)
  float* Pb  = ws + 6029312;   // (512,1536)   -> Hin in-place, later x1b
  float* Sb  = ws + 6815744;   // (512,1536)   -> later pool bufs
  float* xmid= ws + 7602176;   // (B,48,64,64); also hosts pe table until k6
  float* yall = xmg;
  float* Hin  = Pb;
  float* peb  = xmid;          // pe[4096][48] = 196,608 floats, dead before k6
  float* ta   = Sb;
  float* tbuf = Sb + 98304;
  float* ybb  = Sb + 196608;
  float* xpb  = xcg;
  float* xdb  = dtg;
  float* x1b  = Pb;
  float* x1db = Vgb;

  kPE<<<768,256,0,stream>>>(peb);
  kA_front<<<512,256,0,stream>>>(x, n1w, n1b,
      mlnw[0], mlnb[0], mlnw[1], mlnb[1], inproj[0], inproj[1], peb, xmg, Vgb);
  kB_convscan<<<512,384,0,stream>>>(xmg,
      convw[0], convw[1], convb[0], convb[1], xproj[0], xproj[1],
      dtw[0], dtw[1], dtbp[0], dtbp[1], Alog[0], Alog[1],
      xcg, dtg, Bmg, Cmg, Pb, Sb);
  k4_comb  <<<24,256,0,stream>>>(Pb, Sb);
  k5_scan2 <<<512,384,0,stream>>>(dtg, xcg, Bmg, Cmg, Alog[0], Alog[1],
      Dp[0], Dp[1], inproj[0], inproj[1], Vgb, Hin, yall);
  k6_outproj<<<128,256,0,stream>>>(x, yall, yall + 786432, outproj[0], outproj[1], xmid);
  k7_ln_pin <<<128,256,0,stream>>>(xmid, n2w, n2b, fpin, xpb);
  k9_conv3  <<<128,256,0,stream>>>(x, fc1w, fc1b, ta, 1);
  k10_lnrelu<<<32,256,0,stream>>>(ta, fln1w, fln1b, tbuf);
  k9_conv3  <<<128,256,0,stream>>>(tbuf, fc2w, fc2b, ta, 0);
  k10_lnrelu<<<32,256,0,stream>>>(ta, fln2w, fln2b, ybb);
  k13_dw    <<<6144,256,0,stream>>>(xpb, fdw, xdb, 192);
  k14_fus   <<<256,256,0,stream>>>(xdb, ybb, ffus, x1b);
  k13_dw    <<<3072,256,0,stream>>>(x1b, fdwa, x1db, 96);
  k16_out   <<<128,256,0,stream>>>(x1db, xdb, fpout, xmid, (float*)d_out);
}